// Round 6
// baseline (132.490 us; speedup 1.0000x reference)
//
#include <hip/hip_runtime.h>
#include <math.h>

#define HW2048 (2048ull*2048ull)
typedef float f4 __attribute__((ext_vector_type(4)));
typedef float f2 __attribute__((ext_vector_type(2)));

struct BP {
  float P[4][3];   // composed 2-stage bilinear phase weights
  float D2[5];     // d^2 thresholds: L = sum(d2 >= D2[j])
  float cc[5];     // Ts exponent coefs (cc[l] = 4*cc[l-1])
};

__device__ __forceinline__ int ladder5(float dd, const BP& bp) {
  return (dd >= bp.D2[0]) + (dd >= bp.D2[1]) + (dd >= bp.D2[2]) +
         (dd >= bp.D2[3]) + (dd >= bp.D2[4]);
}

// ---------------- K1: img -> C1 + full pyramid p2..p5 (block-local) ---------
__global__ __launch_bounds__(256) void downAll_k(const float* __restrict__ img,
                                                 float* __restrict__ C1,
                                                 float* __restrict__ p2,
                                                 float* __restrict__ p3,
                                                 float* __restrict__ p4,
                                                 float* __restrict__ p5) {
  __shared__ float t2[16][17];
  __shared__ float t3[8][9];
  __shared__ float t4a[4][5];
  int tx = threadIdx.x, ty = threadIdx.y;  // (16,16); grid (32,32,3)
  int X = blockIdx.x * 16 + tx;            // 0..511
  int Y = blockIdx.y * 16 + ty;            // 0..511
  int c = blockIdx.z;
  const float* ip = img + (size_t)c * HW2048 + (size_t)(4 * Y) * 2048 + 4 * X;
  f4 r0 = __builtin_nontemporal_load((const f4*)(ip));
  f4 r1 = __builtin_nontemporal_load((const f4*)(ip + 2048));
  f4 r2 = __builtin_nontemporal_load((const f4*)(ip + 4096));
  f4 r3 = __builtin_nontemporal_load((const f4*)(ip + 6144));
  float a00 = 0.25f * (r0.x + r0.y + r1.x + r1.y);
  float a01 = 0.25f * (r0.z + r0.w + r1.z + r1.w);
  float a10 = 0.25f * (r2.x + r2.y + r3.x + r3.y);
  float a11 = 0.25f * (r2.z + r2.w + r3.z + r3.w);
  float* cp = C1 + (size_t)c * 1048576 + (size_t)(2 * Y) * 1024 + 2 * X;
  f2 u; u.x = a00; u.y = a01; *(f2*)cp = u;
  f2 v; v.x = a10; v.y = a11; *(f2*)(cp + 1024) = v;
  float m = 0.25f * (a00 + a01 + a10 + a11);
  p2[((size_t)c * 512 + Y) * 512 + X] = m;
  t2[ty][tx] = m;
  __syncthreads();
  int tid = ty * 16 + tx;
  if (tid < 64) {
    int y = tid >> 3, x = tid & 7;
    float w = 0.25f * (t2[2*y][2*x] + t2[2*y][2*x+1] + t2[2*y+1][2*x] + t2[2*y+1][2*x+1]);
    p3[((size_t)c * 256 + blockIdx.y * 8 + y) * 256 + blockIdx.x * 8 + x] = w;
    t3[y][x] = w;
  }
  __syncthreads();
  if (tid < 16) {
    int y = tid >> 2, x = tid & 3;
    float w = 0.25f * (t3[2*y][2*x] + t3[2*y][2*x+1] + t3[2*y+1][2*x] + t3[2*y+1][2*x+1]);
    p4[((size_t)c * 128 + blockIdx.y * 4 + y) * 128 + blockIdx.x * 4 + x] = w;
    t4a[y][x] = w;
  }
  __syncthreads();
  if (tid < 4) {
    int y = tid >> 1, x = tid & 1;
    float w = 0.25f * (t4a[2*y][2*x] + t4a[2*y][2*x+1] + t4a[2*y+1][2*x] + t4a[2*y+1][2*x+1]);
    p5[((size_t)c * 64 + blockIdx.y * 2 + y) * 64 + blockIdx.x * 2 + x] = w;
  }
}

// ---------------- bilinear x2 upsample coords (torch align_corners=False) ---
__device__ __forceinline__ void up_coords(int o, int n, int& i0, int& i1, float& w0) {
  int m = o >> 1;
  if (o & 1) { i0 = m; i1 = min(m + 1, n - 1); w0 = 0.75f; }
  else       { i0 = max(m - 1, 0); i1 = m;     w0 = 0.25f; }
}

// ---------------- samplers --------------------------------------------------
// 512-res buffer sampled at 2048-res with composed 2-stage weights (global)
__device__ __forceinline__ void s2c(const float* __restrict__ b, int x0, int y0,
                                    const BP& bp, float o[2][4]) {
  int t = x0 >> 2, ky = y0 >> 2, yph = y0 & 3;
  int c[3], r[3];
#pragma unroll
  for (int j = 0; j < 3; ++j) {
    c[j] = min(max(t - 1 + j, 0), 511);
    r[j] = min(max(ky - 1 + j, 0), 511);
  }
  float v[3][3];
#pragma unroll
  for (int j = 0; j < 3; ++j) {
    const float* row = b + r[j] * 512;
    v[j][0] = row[c[0]]; v[j][1] = row[c[1]]; v[j][2] = row[c[2]];
  }
  const float* wr0 = bp.P[yph];
  const float* wr1 = bp.P[yph + 1];
  float rv0[3], rv1[3];
#pragma unroll
  for (int i = 0; i < 3; ++i) {
    rv0[i] = wr0[0] * v[0][i] + wr0[1] * v[1][i] + wr0[2] * v[2][i];
    rv1[i] = wr1[0] * v[0][i] + wr1[1] * v[1][i] + wr1[2] * v[2][i];
  }
#pragma unroll
  for (int p = 0; p < 4; ++p) {
    o[0][p] = bp.P[p][0] * rv0[0] + bp.P[p][1] * rv0[1] + bp.P[p][2] * rv0[2];
    o[1][p] = bp.P[p][0] * rv1[0] + bp.P[p][1] * rv1[1] + bp.P[p][2] * rv1[2];
  }
}

// same sampling but from the block's pre-clamped LDS U-tile [4][68]
__device__ __forceinline__ void s2c_lds(const float (*t)[68], int tx, int kyr, int yph,
                                        const BP& bp, float o[2][4]) {
  float v[3][3];
#pragma unroll
  for (int j = 0; j < 3; ++j) {
    const float* row = t[kyr + j];
    v[j][0] = row[tx]; v[j][1] = row[tx + 1]; v[j][2] = row[tx + 2];
  }
  const float* wr0 = bp.P[yph];
  const float* wr1 = bp.P[yph + 1];
  float rv0[3], rv1[3];
#pragma unroll
  for (int i = 0; i < 3; ++i) {
    rv0[i] = wr0[0] * v[0][i] + wr0[1] * v[1][i] + wr0[2] * v[2][i];
    rv1[i] = wr1[0] * v[0][i] + wr1[1] * v[1][i] + wr1[2] * v[2][i];
  }
#pragma unroll
  for (int p = 0; p < 4; ++p) {
    o[0][p] = bp.P[p][0] * rv0[0] + bp.P[p][1] * rv0[1] + bp.P[p][2] * rv0[2];
    o[1][p] = bp.P[p][0] * rv1[0] + bp.P[p][1] * rv1[1] + bp.P[p][2] * rv1[2];
  }
}

// C1 (1024^2) sampled at 2048-res (single bilinear stage, global)
__device__ __forceinline__ void s1c(const float* __restrict__ b, int x0, int y0,
                                    float o[2][4]) {
  int q0 = x0 >> 1, qy = y0 >> 1;
  int c[4], r[3];
#pragma unroll
  for (int i = 0; i < 4; ++i) c[i] = min(max(q0 - 1 + i, 0), 1023);
#pragma unroll
  for (int j = 0; j < 3; ++j) r[j] = min(max(qy - 1 + j, 0), 1023);
  float v[3][4];
#pragma unroll
  for (int j = 0; j < 3; ++j) {
    const float* row = b + r[j] * 1024;
    v[j][0] = row[c[0]]; v[j][1] = row[c[1]]; v[j][2] = row[c[2]]; v[j][3] = row[c[3]];
  }
  float rv0[4], rv1[4];
#pragma unroll
  for (int i = 0; i < 4; ++i) {
    rv0[i] = 0.25f * v[0][i] + 0.75f * v[1][i];
    rv1[i] = 0.75f * v[1][i] + 0.25f * v[2][i];
  }
  o[0][0] = 0.25f * rv0[0] + 0.75f * rv0[1];
  o[0][1] = 0.75f * rv0[1] + 0.25f * rv0[2];
  o[0][2] = 0.25f * rv0[1] + 0.75f * rv0[2];
  o[0][3] = 0.75f * rv0[2] + 0.25f * rv0[3];
  o[1][0] = 0.25f * rv1[0] + 0.75f * rv1[1];
  o[1][1] = 0.75f * rv1[1] + 0.25f * rv1[2];
  o[1][2] = 0.25f * rv1[1] + 0.75f * rv1[2];
  o[1][3] = 0.75f * rv1[2] + 0.25f * rv1[3];
}

__device__ __forceinline__ void sampleL(
    int l, int ch, int x0, int y0, int tx, int kyr,
    const float* __restrict__ img, const float* __restrict__ C1,
    const float* __restrict__ p2,
    const float (*tU)[3][4][68], const BP& bp, float o[2][4]) {
  if (l == 0) {
    const float* imgc = img + (size_t)ch * HW2048;
    f4 v0 = *(const f4*)(imgc + (size_t)y0 * 2048 + x0);
    f4 v1 = *(const f4*)(imgc + (size_t)(y0 + 1) * 2048 + x0);
    o[0][0] = v0.x; o[0][1] = v0.y; o[0][2] = v0.z; o[0][3] = v0.w;
    o[1][0] = v1.x; o[1][1] = v1.y; o[1][2] = v1.z; o[1][3] = v1.w;
  } else if (l == 1) {
    s1c(C1 + (size_t)ch * 1048576, x0, y0, o);
  } else if (l == 2) {
    s2c(p2 + (size_t)ch * 262144, x0, y0, bp, o);
  } else {
    s2c_lds(tU[ch][l - 3], tx, kyr, y0 & 3, bp, o);
  }
}

// ---------------- K2: fused upchain + classify + 3-channel blend ------------
// Each block (256x8 px) needs only a 4x66 window of each 512-res upsampled
// level; recompute those windows stage-wise from p3/p4/p5 into LDS (op-
// identical to the old upchain kernel -> bit-identical values), gated by
// analytic block-level level bounds from the fixation geometry.
__global__ __launch_bounds__(256) void fblend_k(
    const float* __restrict__ img, const float* __restrict__ C1,
    const float* __restrict__ p2, const float* __restrict__ p3,
    const float* __restrict__ p4, const float* __restrict__ p5,
    const float* __restrict__ fixs, int nf,
    float* __restrict__ out, BP bp) {
  __shared__ float tU[3][3][4][68];   // [ch][lv-3][row][col]  512-res windows
  __shared__ float tM[3][2][5][38];   // [ch][0]=mid for lv4, [1]=mid for lv5 (256-res)
  __shared__ float tA[3][5][22];      // 128-res window for lv5

  int tx = threadIdx.x, ty = threadIdx.y;       // (64,4)
  int bx = blockIdx.x, by = blockIdx.y;         // grid (8,256)
  int xs = bx * 64 + tx;                        // 0..511
  int yp = by * 4 + ty;                         // 0..1023
  int x0 = xs * 4, y0 = yp * 2;
  size_t ob0 = (size_t)y0 * 2048 + x0;

  // ---- block-level level-range bounds from fixation geometry ----
  int X0 = bx * 256, Y0 = by * 8;
  float bDmin = 3.4e38f, bDmax = 3.4e38f;
  for (int f = 0; f < nf; ++f) {
    float fx = fixs[2 * f], fy = fixs[2 * f + 1];
    float dxm = fmaxf(fmaxf((float)X0 - fx, fx - (float)(X0 + 255)), 0.f);
    float dym = fmaxf(fmaxf((float)Y0 - fy, fy - (float)(Y0 + 7)), 0.f);
    bDmin = fminf(bDmin, dxm * dxm + dym * dym);
    float dxM = fmaxf(fx - (float)X0, (float)(X0 + 255) - fx);
    float dyM = fmaxf(fy - (float)Y0, (float)(Y0 + 7) - fy);
    bDmax = fminf(bDmax, dxM * dxM + dyM * dyM);
  }
  int bLmax = ladder5(bDmax + 2.0f, bp);                 // conservative upper
  int bLmin = ladder5(fmaxf(bDmin - 2.0f, 0.f), bp);     // conservative lower

  if (bLmax == 0) {   // whole block pure img (uniform branch, no syncs inside)
#pragma unroll
    for (int ch = 0; ch < 3; ++ch) {
      const float* imgc = img + (size_t)ch * HW2048;
      f4 v0 = *(const f4*)(imgc + ob0);
      f4 v1 = *(const f4*)(imgc + ob0 + 2048);
      __builtin_nontemporal_store(v0, (f4*)(out + (size_t)ch * HW2048 + ob0));
      __builtin_nontemporal_store(v1, (f4*)(out + (size_t)ch * HW2048 + ob0 + 2048));
    }
    return;
  }

  // ---- stage the needed 512-res level windows into LDS ----
  int sLo = max(bLmin - 1, 3), sHi = min(bLmax, 5);
  int g0 = 2 * by - 1, c0 = 64 * bx - 1;                 // 512-res window base
  if (sLo <= sHi) {                                      // block-uniform
    int m0 = (g0 >> 1) - 1, n0 = (c0 >> 1) - 1;          // 256-res base
    int q0 = (m0 >> 1) - 1, s0 = (n0 >> 1) - 1;          // 128-res base
    int tid = ty * 64 + tx;
    bool lv5 = (sHi == 5), lv4 = (sLo <= 4 && sHi >= 4), lv3 = (sLo == 3);
    // pass 1: tA (p5->128), mid4 (p4->256), U3 (p3->512)
    if (lv5) {
      for (int i = tid; i < 300; i += 256) {
        int ch = i / 100, k = i - ch * 100, r = k / 20, cI = k - r * 20;
        int gy = min(max(q0 + r, 0), 127), gx = min(max(s0 + cI, 0), 127);
        int r0, r1, e0, e1; float wy0, wx0;
        up_coords(gy, 64, r0, r1, wy0);
        up_coords(gx, 64, e0, e1, wx0);
        float wy1 = 1.f - wy0, wx1 = 1.f - wx0;
        const float* s = p5 + ch * 4096;
        tA[ch][r][cI] = wy0 * (wx0 * s[r0*64+e0] + wx1 * s[r0*64+e1])
                      + wy1 * (wx0 * s[r1*64+e0] + wx1 * s[r1*64+e1]);
      }
    }
    if (lv4) {
      for (int i = tid; i < 540; i += 256) {
        int ch = i / 180, k = i - ch * 180, r = k / 36, cI = k - r * 36;
        int gy = min(max(m0 + r, 0), 255), gx = min(max(n0 + cI, 0), 255);
        int r0, r1, e0, e1; float wy0, wx0;
        up_coords(gy, 128, r0, r1, wy0);
        up_coords(gx, 128, e0, e1, wx0);
        float wy1 = 1.f - wy0, wx1 = 1.f - wx0;
        const float* s = p4 + ch * 16384;
        tM[ch][0][r][cI] = wy0 * (wx0 * s[r0*128+e0] + wx1 * s[r0*128+e1])
                         + wy1 * (wx0 * s[r1*128+e0] + wx1 * s[r1*128+e1]);
      }
    }
    if (lv3) {
      for (int i = tid; i < 792; i += 256) {
        int ch = i / 264, k = i - ch * 264, r = k / 66, cI = k - r * 66;
        int gy = min(max(g0 + r, 0), 511), gx = min(max(c0 + cI, 0), 511);
        int r0, r1, e0, e1; float wy0, wx0;
        up_coords(gy, 256, r0, r1, wy0);
        up_coords(gx, 256, e0, e1, wx0);
        float wy1 = 1.f - wy0, wx1 = 1.f - wx0;
        const float* s = p3 + ch * 65536;
        tU[ch][0][r][cI] = wy0 * (wx0 * s[r0*256+e0] + wx1 * s[r0*256+e1])
                         + wy1 * (wx0 * s[r1*256+e0] + wx1 * s[r1*256+e1]);
      }
    }
    __syncthreads();
    // pass 2: mid5 (tA->256), U4 (mid4->512)
    if (lv5) {
      for (int i = tid; i < 540; i += 256) {
        int ch = i / 180, k = i - ch * 180, r = k / 36, cI = k - r * 36;
        int gy = min(max(m0 + r, 0), 255), gx = min(max(n0 + cI, 0), 255);
        int r0, r1, e0, e1; float wy0, wx0;
        up_coords(gy, 128, r0, r1, wy0);
        up_coords(gx, 128, e0, e1, wx0);
        float wy1 = 1.f - wy0, wx1 = 1.f - wx0;
        tM[ch][1][r][cI] = wy0 * (wx0 * tA[ch][r0-q0][e0-s0] + wx1 * tA[ch][r0-q0][e1-s0])
                         + wy1 * (wx0 * tA[ch][r1-q0][e0-s0] + wx1 * tA[ch][r1-q0][e1-s0]);
      }
    }
    if (lv4) {
      for (int i = tid; i < 792; i += 256) {
        int ch = i / 264, k = i - ch * 264, r = k / 66, cI = k - r * 66;
        int gy = min(max(g0 + r, 0), 511), gx = min(max(c0 + cI, 0), 511);
        int r0, r1, e0, e1; float wy0, wx0;
        up_coords(gy, 256, r0, r1, wy0);
        up_coords(gx, 256, e0, e1, wx0);
        float wy1 = 1.f - wy0, wx1 = 1.f - wx0;
        tU[ch][1][r][cI] = wy0 * (wx0 * tM[ch][0][r0-m0][e0-n0] + wx1 * tM[ch][0][r0-m0][e1-n0])
                         + wy1 * (wx0 * tM[ch][0][r1-m0][e0-n0] + wx1 * tM[ch][0][r1-m0][e1-n0]);
      }
    }
    __syncthreads();
    // pass 3: U5 (mid5->512)
    if (lv5) {
      for (int i = tid; i < 792; i += 256) {
        int ch = i / 264, k = i - ch * 264, r = k / 66, cI = k - r * 66;
        int gy = min(max(g0 + r, 0), 511), gx = min(max(c0 + cI, 0), 511);
        int r0, r1, e0, e1; float wy0, wx0;
        up_coords(gy, 256, r0, r1, wy0);
        up_coords(gx, 256, e0, e1, wx0);
        float wy1 = 1.f - wy0, wx1 = 1.f - wx0;
        tU[ch][2][r][cI] = wy0 * (wx0 * tM[ch][1][r0-m0][e0-n0] + wx1 * tM[ch][1][r0-m0][e1-n0])
                         + wy1 * (wx0 * tM[ch][1][r1-m0][e0-n0] + wx1 * tM[ch][1][r1-m0][e1-n0]);
      }
    }
    __syncthreads();
  }
  // (no __syncthreads below this point; per-thread early-outs are safe)

  // ---- per-span min squared distance over fixations ----
  float d2[2][4];
#pragma unroll
  for (int j = 0; j < 2; ++j)
#pragma unroll
    for (int i = 0; i < 4; ++i) d2[j][i] = 3.4e38f;
  for (int f = 0; f < nf; ++f) {
    float dx0 = (float)x0 - fixs[2 * f], dy0 = (float)y0 - fixs[2 * f + 1];
#pragma unroll
    for (int j = 0; j < 2; ++j) {
      float dy = dy0 + (float)j, dy2 = dy * dy;
#pragma unroll
      for (int i = 0; i < 4; ++i) {
        float dx = dx0 + (float)i;
        d2[j][i] = fminf(d2[j][i], dx * dx + dy2);
      }
    }
  }

  bool uniformB = (bLmin == bLmax);
  int lmax;
  bool mixed;
  if (uniformB) {
    lmax = bLmax; mixed = false;
  } else {
    float dmn = d2[0][0], dmx = d2[0][0];
#pragma unroll
    for (int j = 0; j < 2; ++j)
#pragma unroll
      for (int i = 0; i < 4; ++i) {
        dmn = fminf(dmn, d2[j][i]);
        dmx = fmaxf(dmx, d2[j][i]);
      }
    lmax = ladder5(dmx, bp);
    int lmin = ladder5(dmn, bp);
    mixed = (lmin != lmax);
  }

  if (lmax == 0) {   // span pure img
#pragma unroll
    for (int ch = 0; ch < 3; ++ch) {
      const float* imgc = img + (size_t)ch * HW2048;
      f4 v0 = *(const f4*)(imgc + ob0);
      f4 v1 = *(const f4*)(imgc + ob0 + 2048);
      __builtin_nontemporal_store(v0, (f4*)(out + (size_t)ch * HW2048 + ob0));
      __builtin_nontemporal_store(v1, (f4*)(out + (size_t)ch * HW2048 + ob0 + 2048));
    }
    return;
  }

  float thr  = (lmax == 1) ? bp.D2[0] : (lmax == 2) ? bp.D2[1] :
               (lmax == 3) ? bp.D2[2] : (lmax == 4) ? bp.D2[3] : bp.D2[4];
  float cm_A = (lmax == 1) ? bp.cc[0] : (lmax == 2) ? bp.cc[1] :
               (lmax == 3) ? bp.cc[2] : (lmax == 4) ? bp.cc[3] : bp.cc[4];
  float cm_B = (lmax <= 2) ? bp.cc[0] : (lmax == 3) ? bp.cc[1] :
               (lmax == 4) ? bp.cc[2] : bp.cc[3];
  bool top5 = (lmax >= 5);

  // ---- per-pixel B (fast-math), shared by all channels ----
  float Bv[2][4];
  bool  tp[2][4];
#pragma unroll
  for (int j = 0; j < 2; ++j)
#pragma unroll
    for (int i = 0; i < 4; ++i) {
      float dd = d2[j][i];
      bool top = uniformB ? true : (dd >= thr);
      tp[j][i] = top;
      float d = dd * __frsqrt_rn(dd);
      float R = 18.75f * __frcp_rn(d + 18.75f);
      float R2 = R * R;
      float cm = top ? cm_A : cm_B;
      float tsm = __expf(-cm * R2);                 // Ts[l-1]
      float t2 = tsm * tsm;
      float tsL = (top && top5) ? 0.f : t2 * t2;    // Ts[l] = Ts[l-1]^4
      float B = (0.5f - tsL) * __frcp_rn(tsm - tsL + 1e-5f);
      if (!top && lmax == 1) B = 0.f;
      Bv[j][i] = B;
    }

  // ---- per-channel sampling + blend ----
  int kyr = ty >> 1;   // row offset of this span inside the LDS window
#pragma unroll
  for (int ch = 0; ch < 3; ++ch) {
    float sA[2][4], sB[2][4], sC[2][4];
    sampleL(lmax,     ch, x0, y0, tx, kyr, img, C1, p2, tU, bp, sA);
    sampleL(lmax - 1, ch, x0, y0, tx, kyr, img, C1, p2, tU, bp, sB);
#pragma unroll
    for (int j = 0; j < 2; ++j)
#pragma unroll
      for (int i = 0; i < 4; ++i) sC[j][i] = sB[j][i];
    if (mixed && lmax >= 2)
      sampleL(lmax - 2, ch, x0, y0, tx, kyr, img, C1, p2, tU, bp, sC);

    float res[2][4];
#pragma unroll
    for (int j = 0; j < 2; ++j)
#pragma unroll
      for (int i = 0; i < 4; ++i) {
        float B = Bv[j][i];
        bool top = tp[j][i];
        float hi = top ? sA[j][i] : sB[j][i];
        float lo = top ? sB[j][i] : sC[j][i];
        res[j][i] = B * lo + (1.f - B) * hi;
      }

    f4 v0, v1;
    v0.x = res[0][0]; v0.y = res[0][1]; v0.z = res[0][2]; v0.w = res[0][3];
    v1.x = res[1][0]; v1.y = res[1][1]; v1.z = res[1][2]; v1.w = res[1][3];
    __builtin_nontemporal_store(v0, (f4*)(out + (size_t)ch * HW2048 + ob0));
    __builtin_nontemporal_store(v1, (f4*)(out + (size_t)ch * HW2048 + ob0 + 2048));
  }
}

extern "C" void kernel_launch(void* const* d_in, const int* in_sizes, int n_in,
                              void* d_out, int out_size, void* d_ws, size_t ws_size,
                              hipStream_t stream) {
  const float* img  = (const float*)d_in[0];
  const float* fixs = (const float*)d_in[1];
  int nf = in_sizes[1] / 2;
  float* out = (float*)d_out;
  float* ws  = (float*)d_ws;

  BP bp;
  const double sig = 0.248, Kd = 3.0, Pd = 7.5, Ad = 2.5;
  double obv = sqrt(log(2.0) / Kd) * sig;
  for (int j = 0; j < 5; ++j) {
    double om = obv * pow(2.0, 2 - j);
    double Dj = Pd * Ad * (1.0 / om - 1.0);
    bp.D2[j] = (float)(Dj * Dj);
  }
  for (int X = 0; X < 5; ++X)
    bp.cc[X] = (float)(Kd * pow(2.0, 2.0 * (X - 2)) / (sig * sig));
  const float Pt[4][3] = {{0.375f, 0.625f, 0.f},
                          {0.1875f, 0.75f, 0.0625f},
                          {0.0625f, 0.75f, 0.1875f},
                          {0.f, 0.625f, 0.375f}};
  for (int a = 0; a < 4; ++a) for (int t = 0; t < 3; ++t) bp.P[a][t] = Pt[a][t];

  size_t o = 0;
  float* C1 = ws + o; o += 3ull * 1024 * 1024;
  float* p2 = ws + o; o += 3ull * 512 * 512;
  float* p3 = ws + o; o += 3ull * 256 * 256;
  float* p4 = ws + o; o += 3ull * 128 * 128;
  float* p5 = ws + o; o += 3ull * 64 * 64;

  downAll_k <<<dim3(32, 32, 3), dim3(16, 16), 0, stream>>>(img, C1, p2, p3, p4, p5);
  fblend_k  <<<dim3(8, 256),    dim3(64, 4),  0, stream>>>(img, C1, p2, p3, p4, p5,
                                                           fixs, nf, out, bp);
}

// Round 7
// 131.112 us; speedup vs baseline: 1.0105x; 1.0105x over previous
//
#include <hip/hip_runtime.h>
#include <math.h>

#define HW2048 (2048ull*2048ull)
typedef float f4 __attribute__((ext_vector_type(4)));
typedef float f2 __attribute__((ext_vector_type(2)));

struct BP {
  float P[4][3];   // composed 2-stage bilinear phase weights
  float D2[5];     // d^2 thresholds: L = sum(d2 >= D2[j])
  float cc[5];     // Ts exponent coefs (cc[l] = 4*cc[l-1])
};

__device__ __forceinline__ int ladder5(float dd, const BP& bp) {
  return (dd >= bp.D2[0]) + (dd >= bp.D2[1]) + (dd >= bp.D2[2]) +
         (dd >= bp.D2[3]) + (dd >= bp.D2[4]);
}

// ---------------- K1: img -> C1 + full pyramid p2..p5 (block-local) ---------
__global__ __launch_bounds__(256) void downAll_k(const float* __restrict__ img,
                                                 float* __restrict__ C1,
                                                 float* __restrict__ p2,
                                                 float* __restrict__ p3,
                                                 float* __restrict__ p4,
                                                 float* __restrict__ p5) {
  __shared__ float t2[16][17];
  __shared__ float t3[8][9];
  __shared__ float t4a[4][5];
  int tx = threadIdx.x, ty = threadIdx.y;  // (16,16); grid (32,32,3)
  int X = blockIdx.x * 16 + tx;            // 0..511
  int Y = blockIdx.y * 16 + ty;            // 0..511
  int c = blockIdx.z;
  const float* ip = img + (size_t)c * HW2048 + (size_t)(4 * Y) * 2048 + 4 * X;
  f4 r0 = __builtin_nontemporal_load((const f4*)(ip));
  f4 r1 = __builtin_nontemporal_load((const f4*)(ip + 2048));
  f4 r2 = __builtin_nontemporal_load((const f4*)(ip + 4096));
  f4 r3 = __builtin_nontemporal_load((const f4*)(ip + 6144));
  float a00 = 0.25f * (r0.x + r0.y + r1.x + r1.y);
  float a01 = 0.25f * (r0.z + r0.w + r1.z + r1.w);
  float a10 = 0.25f * (r2.x + r2.y + r3.x + r3.y);
  float a11 = 0.25f * (r2.z + r2.w + r3.z + r3.w);
  float* cp = C1 + (size_t)c * 1048576 + (size_t)(2 * Y) * 1024 + 2 * X;
  f2 u; u.x = a00; u.y = a01; *(f2*)cp = u;
  f2 v; v.x = a10; v.y = a11; *(f2*)(cp + 1024) = v;
  float m = 0.25f * (a00 + a01 + a10 + a11);
  p2[((size_t)c * 512 + Y) * 512 + X] = m;
  t2[ty][tx] = m;
  __syncthreads();
  int tid = ty * 16 + tx;
  if (tid < 64) {
    int y = tid >> 3, x = tid & 7;
    float w = 0.25f * (t2[2*y][2*x] + t2[2*y][2*x+1] + t2[2*y+1][2*x] + t2[2*y+1][2*x+1]);
    p3[((size_t)c * 256 + blockIdx.y * 8 + y) * 256 + blockIdx.x * 8 + x] = w;
    t3[y][x] = w;
  }
  __syncthreads();
  if (tid < 16) {
    int y = tid >> 2, x = tid & 3;
    float w = 0.25f * (t3[2*y][2*x] + t3[2*y][2*x+1] + t3[2*y+1][2*x] + t3[2*y+1][2*x+1]);
    p4[((size_t)c * 128 + blockIdx.y * 4 + y) * 128 + blockIdx.x * 4 + x] = w;
    t4a[y][x] = w;
  }
  __syncthreads();
  if (tid < 4) {
    int y = tid >> 1, x = tid & 1;
    float w = 0.25f * (t4a[2*y][2*x] + t4a[2*y][2*x+1] + t4a[2*y+1][2*x] + t4a[2*y+1][2*x+1]);
    p5[((size_t)c * 64 + blockIdx.y * 2 + y) * 64 + blockIdx.x * 2 + x] = w;
  }
}

// ---------------- bilinear x2 upsample coords (torch align_corners=False) ---
__device__ __forceinline__ void up_coords(int o, int n, int& i0, int& i1, float& w0) {
  int m = o >> 1;
  if (o & 1) { i0 = m; i1 = min(m + 1, n - 1); w0 = 0.75f; }
  else       { i0 = max(m - 1, 0); i1 = m;     w0 = 0.25f; }
}

// ---------------- samplers --------------------------------------------------
// 512-res buffer sampled at 2048-res with composed 2-stage weights (global)
__device__ __forceinline__ void s2c(const float* __restrict__ b, int x0, int y0,
                                    const BP& bp, float o[2][4]) {
  int t = x0 >> 2, ky = y0 >> 2, yph = y0 & 3;
  int c[3], r[3];
#pragma unroll
  for (int j = 0; j < 3; ++j) {
    c[j] = min(max(t - 1 + j, 0), 511);
    r[j] = min(max(ky - 1 + j, 0), 511);
  }
  float v[3][3];
#pragma unroll
  for (int j = 0; j < 3; ++j) {
    const float* row = b + r[j] * 512;
    v[j][0] = row[c[0]]; v[j][1] = row[c[1]]; v[j][2] = row[c[2]];
  }
  const float* wr0 = bp.P[yph];
  const float* wr1 = bp.P[yph + 1];
  float rv0[3], rv1[3];
#pragma unroll
  for (int i = 0; i < 3; ++i) {
    rv0[i] = wr0[0] * v[0][i] + wr0[1] * v[1][i] + wr0[2] * v[2][i];
    rv1[i] = wr1[0] * v[0][i] + wr1[1] * v[1][i] + wr1[2] * v[2][i];
  }
#pragma unroll
  for (int p = 0; p < 4; ++p) {
    o[0][p] = bp.P[p][0] * rv0[0] + bp.P[p][1] * rv0[1] + bp.P[p][2] * rv0[2];
    o[1][p] = bp.P[p][0] * rv1[0] + bp.P[p][1] * rv1[1] + bp.P[p][2] * rv1[2];
  }
}

// same sampling but from the block's pre-clamped LDS U-tile [4][68]
__device__ __forceinline__ void s2c_lds(const float (*t)[68], int tx, int kyr, int yph,
                                        const BP& bp, float o[2][4]) {
  float v[3][3];
#pragma unroll
  for (int j = 0; j < 3; ++j) {
    const float* row = t[kyr + j];
    v[j][0] = row[tx]; v[j][1] = row[tx + 1]; v[j][2] = row[tx + 2];
  }
  const float* wr0 = bp.P[yph];
  const float* wr1 = bp.P[yph + 1];
  float rv0[3], rv1[3];
#pragma unroll
  for (int i = 0; i < 3; ++i) {
    rv0[i] = wr0[0] * v[0][i] + wr0[1] * v[1][i] + wr0[2] * v[2][i];
    rv1[i] = wr1[0] * v[0][i] + wr1[1] * v[1][i] + wr1[2] * v[2][i];
  }
#pragma unroll
  for (int p = 0; p < 4; ++p) {
    o[0][p] = bp.P[p][0] * rv0[0] + bp.P[p][1] * rv0[1] + bp.P[p][2] * rv0[2];
    o[1][p] = bp.P[p][0] * rv1[0] + bp.P[p][1] * rv1[1] + bp.P[p][2] * rv1[2];
  }
}

// C1 (1024^2) sampled at 2048-res (single bilinear stage, global)
__device__ __forceinline__ void s1c(const float* __restrict__ b, int x0, int y0,
                                    float o[2][4]) {
  int q0 = x0 >> 1, qy = y0 >> 1;
  int c[4], r[3];
#pragma unroll
  for (int i = 0; i < 4; ++i) c[i] = min(max(q0 - 1 + i, 0), 1023);
#pragma unroll
  for (int j = 0; j < 3; ++j) r[j] = min(max(qy - 1 + j, 0), 1023);
  float v[3][4];
#pragma unroll
  for (int j = 0; j < 3; ++j) {
    const float* row = b + r[j] * 1024;
    v[j][0] = row[c[0]]; v[j][1] = row[c[1]]; v[j][2] = row[c[2]]; v[j][3] = row[c[3]];
  }
  float rv0[4], rv1[4];
#pragma unroll
  for (int i = 0; i < 4; ++i) {
    rv0[i] = 0.25f * v[0][i] + 0.75f * v[1][i];
    rv1[i] = 0.75f * v[1][i] + 0.25f * v[2][i];
  }
  o[0][0] = 0.25f * rv0[0] + 0.75f * rv0[1];
  o[0][1] = 0.75f * rv0[1] + 0.25f * rv0[2];
  o[0][2] = 0.25f * rv0[1] + 0.75f * rv0[2];
  o[0][3] = 0.75f * rv0[2] + 0.25f * rv0[3];
  o[1][0] = 0.25f * rv1[0] + 0.75f * rv1[1];
  o[1][1] = 0.75f * rv1[1] + 0.25f * rv1[2];
  o[1][2] = 0.25f * rv1[1] + 0.75f * rv1[2];
  o[1][3] = 0.75f * rv1[2] + 0.25f * rv1[3];
}

__device__ __forceinline__ void sampleL(
    int l, int ch, int x0, int y0, int tx, int kyr,
    const float* __restrict__ img, const float* __restrict__ C1,
    const float* __restrict__ p2,
    const float (*tU)[3][4][68], const BP& bp, float o[2][4]) {
  if (l == 0) {
    const float* imgc = img + (size_t)ch * HW2048;
    f4 v0 = *(const f4*)(imgc + (size_t)y0 * 2048 + x0);
    f4 v1 = *(const f4*)(imgc + (size_t)(y0 + 1) * 2048 + x0);
    o[0][0] = v0.x; o[0][1] = v0.y; o[0][2] = v0.z; o[0][3] = v0.w;
    o[1][0] = v1.x; o[1][1] = v1.y; o[1][2] = v1.z; o[1][3] = v1.w;
  } else if (l == 1) {
    s1c(C1 + (size_t)ch * 1048576, x0, y0, o);
  } else if (l == 2) {
    s2c(p2 + (size_t)ch * 262144, x0, y0, bp, o);
  } else {
    s2c_lds(tU[ch][l - 3], tx, kyr, y0 & 3, bp, o);
  }
}

// ---------------- K2: fused upchain + classify + 3-channel blend ------------
// Staging restructured (vs R6): three division-free passes with (tx,ty)-mapped
// sites; coordinates/weights computed ONCE per site and shared across all 3
// channels and across levels (tM0/tM1 share the 256-res lattice; tU0/1/2
// share the 512-res lattice). Same math ops per texel as the old upchain ->
// values bit-identical.
__global__ __launch_bounds__(256) void fblend_k(
    const float* __restrict__ img, const float* __restrict__ C1,
    const float* __restrict__ p2, const float* __restrict__ p3,
    const float* __restrict__ p4, const float* __restrict__ p5,
    const float* __restrict__ fixs, int nf,
    float* __restrict__ out, BP bp) {
  __shared__ float tU[3][3][4][68];   // [ch][lv-3][row][col]  512-res windows
  __shared__ float tM[3][2][5][38];   // [ch][0]=mid for lv4, [1]=mid for lv5 (256-res)
  __shared__ float tA[3][5][22];      // 128-res window for lv5

  int tx = threadIdx.x, ty = threadIdx.y;       // (64,4)
  int bx = blockIdx.x, by = blockIdx.y;         // grid (8,256)
  int xs = bx * 64 + tx;                        // 0..511
  int yp = by * 4 + ty;                         // 0..1023
  int x0 = xs * 4, y0 = yp * 2;
  size_t ob0 = (size_t)y0 * 2048 + x0;

  // ---- block-level level-range bounds from fixation geometry ----
  int X0 = bx * 256, Y0 = by * 8;
  float bDmin = 3.4e38f, bDmax = 3.4e38f;
  for (int f = 0; f < nf; ++f) {
    float fx = fixs[2 * f], fy = fixs[2 * f + 1];
    float dxm = fmaxf(fmaxf((float)X0 - fx, fx - (float)(X0 + 255)), 0.f);
    float dym = fmaxf(fmaxf((float)Y0 - fy, fy - (float)(Y0 + 7)), 0.f);
    bDmin = fminf(bDmin, dxm * dxm + dym * dym);
    float dxM = fmaxf(fx - (float)X0, (float)(X0 + 255) - fx);
    float dyM = fmaxf(fy - (float)Y0, (float)(Y0 + 7) - fy);
    bDmax = fminf(bDmax, dxM * dxM + dyM * dyM);
  }
  int bLmax = ladder5(bDmax + 2.0f, bp);                 // conservative upper
  int bLmin = ladder5(fmaxf(bDmin - 2.0f, 0.f), bp);     // conservative lower

  if (bLmax == 0) {   // whole block pure img (uniform branch, no syncs inside)
#pragma unroll
    for (int ch = 0; ch < 3; ++ch) {
      const float* imgc = img + (size_t)ch * HW2048;
      f4 v0 = *(const f4*)(imgc + ob0);
      f4 v1 = *(const f4*)(imgc + ob0 + 2048);
      __builtin_nontemporal_store(v0, (f4*)(out + (size_t)ch * HW2048 + ob0));
      __builtin_nontemporal_store(v1, (f4*)(out + (size_t)ch * HW2048 + ob0 + 2048));
    }
    return;
  }

  // ---- stage the needed 512-res level windows into LDS ----
  int sLo = max(bLmin - 1, 3), sHi = min(bLmax, 5);
  int g0 = 2 * by - 1, c0 = 64 * bx - 1;                 // 512-res window base
  if (sLo <= sHi) {                                      // block-uniform
    int m0 = (g0 >> 1) - 1, n0 = (c0 >> 1) - 1;          // 256-res base
    int q0 = (m0 >> 1) - 1, s0 = (n0 >> 1) - 1;          // 128-res base
    bool lv5 = (sHi == 5), lv4 = (sLo <= 4 && sHi >= 4), lv3 = (sLo == 3);

    // pass A: tA (p5 -> 128-res window [5][20]); cols tx<20, rows ty + row 4
    if (lv5) {
      if (tx < 20) {
#pragma unroll
        for (int rr = 0; rr < 2; ++rr) {
          int r = (rr == 0) ? ty : 4;
          if (rr == 0 || ty == 0) {
            int gy = min(max(q0 + r, 0), 127);
            int gx = min(max(s0 + tx, 0), 127);
            int r0, r1, e0, e1; float wy0, wx0;
            up_coords(gy, 64, r0, r1, wy0);
            up_coords(gx, 64, e0, e1, wx0);
            float wy1 = 1.f - wy0, wx1 = 1.f - wx0;
            int i00 = r0*64+e0, i01 = r0*64+e1, i10 = r1*64+e0, i11 = r1*64+e1;
#pragma unroll
            for (int ch = 0; ch < 3; ++ch) {
              const float* s = p5 + ch * 4096;
              tA[ch][r][tx] = wy0 * (wx0 * s[i00] + wx1 * s[i01])
                            + wy1 * (wx0 * s[i10] + wx1 * s[i11]);
            }
          }
        }
      }
      __syncthreads();
    }

    // pass B: 256-res sites [5][36]; tM0 from p4, tM1 from tA, shared coords
    if (lv4 || lv5) {
      if (tx < 36) {
#pragma unroll
        for (int rr = 0; rr < 2; ++rr) {
          int r = (rr == 0) ? ty : 4;
          if (rr == 0 || ty == 0) {
            int gy = min(max(m0 + r, 0), 255);
            int gx = min(max(n0 + tx, 0), 255);
            int r0, r1, e0, e1; float wy0, wx0;
            up_coords(gy, 128, r0, r1, wy0);
            up_coords(gx, 128, e0, e1, wx0);
            float wy1 = 1.f - wy0, wx1 = 1.f - wx0;
            if (lv4) {
              int i00 = r0*128+e0, i01 = r0*128+e1, i10 = r1*128+e0, i11 = r1*128+e1;
#pragma unroll
              for (int ch = 0; ch < 3; ++ch) {
                const float* s = p4 + ch * 16384;
                tM[ch][0][r][tx] = wy0 * (wx0 * s[i00] + wx1 * s[i01])
                                 + wy1 * (wx0 * s[i10] + wx1 * s[i11]);
              }
            }
            if (lv5) {
              int a0 = r0 - q0, a1 = r1 - q0, b0 = e0 - s0, b1 = e1 - s0;
#pragma unroll
              for (int ch = 0; ch < 3; ++ch)
                tM[ch][1][r][tx] = wy0 * (wx0 * tA[ch][a0][b0] + wx1 * tA[ch][a0][b1])
                                 + wy1 * (wx0 * tA[ch][a1][b0] + wx1 * tA[ch][a1][b1]);
            }
          }
        }
      }
      __syncthreads();
    }

    // pass C: 512-res sites [4][66]; tU0 from p3, tU1 from tM0, tU2 from tM1
    {
#pragma unroll
      for (int cc2 = 0; cc2 < 2; ++cc2) {
        int cI = (cc2 == 0) ? tx : 64 + tx;
        if (cc2 == 0 || tx < 2) {
          int gy = min(max(g0 + ty, 0), 511);
          int gx = min(max(c0 + cI, 0), 511);
          int r0, r1, e0, e1; float wy0, wx0;
          up_coords(gy, 256, r0, r1, wy0);
          up_coords(gx, 256, e0, e1, wx0);
          float wy1 = 1.f - wy0, wx1 = 1.f - wx0;
          if (lv3) {
            int i00 = r0*256+e0, i01 = r0*256+e1, i10 = r1*256+e0, i11 = r1*256+e1;
#pragma unroll
            for (int ch = 0; ch < 3; ++ch) {
              const float* s = p3 + ch * 65536;
              tU[ch][0][ty][cI] = wy0 * (wx0 * s[i00] + wx1 * s[i01])
                                + wy1 * (wx0 * s[i10] + wx1 * s[i11]);
            }
          }
          int a0 = r0 - m0, a1 = r1 - m0, b0 = e0 - n0, b1 = e1 - n0;
          if (lv4) {
#pragma unroll
            for (int ch = 0; ch < 3; ++ch)
              tU[ch][1][ty][cI] = wy0 * (wx0 * tM[ch][0][a0][b0] + wx1 * tM[ch][0][a0][b1])
                                + wy1 * (wx0 * tM[ch][0][a1][b0] + wx1 * tM[ch][0][a1][b1]);
          }
          if (lv5) {
#pragma unroll
            for (int ch = 0; ch < 3; ++ch)
              tU[ch][2][ty][cI] = wy0 * (wx0 * tM[ch][1][a0][b0] + wx1 * tM[ch][1][a0][b1])
                                + wy1 * (wx0 * tM[ch][1][a1][b0] + wx1 * tM[ch][1][a1][b1]);
          }
        }
      }
      __syncthreads();
    }
  }
  // (no __syncthreads below this point; per-thread early-outs are safe)

  // ---- per-span min squared distance over fixations ----
  float d2[2][4];
#pragma unroll
  for (int j = 0; j < 2; ++j)
#pragma unroll
    for (int i = 0; i < 4; ++i) d2[j][i] = 3.4e38f;
  for (int f = 0; f < nf; ++f) {
    float dx0 = (float)x0 - fixs[2 * f], dy0 = (float)y0 - fixs[2 * f + 1];
#pragma unroll
    for (int j = 0; j < 2; ++j) {
      float dy = dy0 + (float)j, dy2 = dy * dy;
#pragma unroll
      for (int i = 0; i < 4; ++i) {
        float dx = dx0 + (float)i;
        d2[j][i] = fminf(d2[j][i], dx * dx + dy2);
      }
    }
  }

  bool uniformB = (bLmin == bLmax);
  int lmax;
  bool mixed;
  if (uniformB) {
    lmax = bLmax; mixed = false;
  } else {
    float dmn = d2[0][0], dmx = d2[0][0];
#pragma unroll
    for (int j = 0; j < 2; ++j)
#pragma unroll
      for (int i = 0; i < 4; ++i) {
        dmn = fminf(dmn, d2[j][i]);
        dmx = fmaxf(dmx, d2[j][i]);
      }
    lmax = ladder5(dmx, bp);
    int lmin = ladder5(dmn, bp);
    mixed = (lmin != lmax);
  }

  if (lmax == 0) {   // span pure img
#pragma unroll
    for (int ch = 0; ch < 3; ++ch) {
      const float* imgc = img + (size_t)ch * HW2048;
      f4 v0 = *(const f4*)(imgc + ob0);
      f4 v1 = *(const f4*)(imgc + ob0 + 2048);
      __builtin_nontemporal_store(v0, (f4*)(out + (size_t)ch * HW2048 + ob0));
      __builtin_nontemporal_store(v1, (f4*)(out + (size_t)ch * HW2048 + ob0 + 2048));
    }
    return;
  }

  float thr  = (lmax == 1) ? bp.D2[0] : (lmax == 2) ? bp.D2[1] :
               (lmax == 3) ? bp.D2[2] : (lmax == 4) ? bp.D2[3] : bp.D2[4];
  float cm_A = (lmax == 1) ? bp.cc[0] : (lmax == 2) ? bp.cc[1] :
               (lmax == 3) ? bp.cc[2] : (lmax == 4) ? bp.cc[3] : bp.cc[4];
  float cm_B = (lmax <= 2) ? bp.cc[0] : (lmax == 3) ? bp.cc[1] :
               (lmax == 4) ? bp.cc[2] : bp.cc[3];
  bool top5 = (lmax >= 5);

  // ---- per-pixel B (fast-math), shared by all channels ----
  float Bv[2][4];
  bool  tp[2][4];
#pragma unroll
  for (int j = 0; j < 2; ++j)
#pragma unroll
    for (int i = 0; i < 4; ++i) {
      float dd = d2[j][i];
      bool top = uniformB ? true : (dd >= thr);
      tp[j][i] = top;
      float d = dd * __frsqrt_rn(dd);
      float R = 18.75f * __frcp_rn(d + 18.75f);
      float R2 = R * R;
      float cm = top ? cm_A : cm_B;
      float tsm = __expf(-cm * R2);                 // Ts[l-1]
      float t2 = tsm * tsm;
      float tsL = (top && top5) ? 0.f : t2 * t2;    // Ts[l] = Ts[l-1]^4
      float B = (0.5f - tsL) * __frcp_rn(tsm - tsL + 1e-5f);
      if (!top && lmax == 1) B = 0.f;
      Bv[j][i] = B;
    }

  // ---- per-channel sampling + blend ----
  int kyr = ty >> 1;   // row offset of this span inside the LDS window
#pragma unroll
  for (int ch = 0; ch < 3; ++ch) {
    float sA[2][4], sB[2][4], sC[2][4];
    sampleL(lmax,     ch, x0, y0, tx, kyr, img, C1, p2, tU, bp, sA);
    sampleL(lmax - 1, ch, x0, y0, tx, kyr, img, C1, p2, tU, bp, sB);
#pragma unroll
    for (int j = 0; j < 2; ++j)
#pragma unroll
      for (int i = 0; i < 4; ++i) sC[j][i] = sB[j][i];
    if (mixed && lmax >= 2)
      sampleL(lmax - 2, ch, x0, y0, tx, kyr, img, C1, p2, tU, bp, sC);

    float res[2][4];
#pragma unroll
    for (int j = 0; j < 2; ++j)
#pragma unroll
      for (int i = 0; i < 4; ++i) {
        float B = Bv[j][i];
        bool top = tp[j][i];
        float hi = top ? sA[j][i] : sB[j][i];
        float lo = top ? sB[j][i] : sC[j][i];
        res[j][i] = B * lo + (1.f - B) * hi;
      }

    f4 v0, v1;
    v0.x = res[0][0]; v0.y = res[0][1]; v0.z = res[0][2]; v0.w = res[0][3];
    v1.x = res[1][0]; v1.y = res[1][1]; v1.z = res[1][2]; v1.w = res[1][3];
    __builtin_nontemporal_store(v0, (f4*)(out + (size_t)ch * HW2048 + ob0));
    __builtin_nontemporal_store(v1, (f4*)(out + (size_t)ch * HW2048 + ob0 + 2048));
  }
}

extern "C" void kernel_launch(void* const* d_in, const int* in_sizes, int n_in,
                              void* d_out, int out_size, void* d_ws, size_t ws_size,
                              hipStream_t stream) {
  const float* img  = (const float*)d_in[0];
  const float* fixs = (const float*)d_in[1];
  int nf = in_sizes[1] / 2;
  float* out = (float*)d_out;
  float* ws  = (float*)d_ws;

  BP bp;
  const double sig = 0.248, Kd = 3.0, Pd = 7.5, Ad = 2.5;
  double obv = sqrt(log(2.0) / Kd) * sig;
  for (int j = 0; j < 5; ++j) {
    double om = obv * pow(2.0, 2 - j);
    double Dj = Pd * Ad * (1.0 / om - 1.0);
    bp.D2[j] = (float)(Dj * Dj);
  }
  for (int X = 0; X < 5; ++X)
    bp.cc[X] = (float)(Kd * pow(2.0, 2.0 * (X - 2)) / (sig * sig));
  const float Pt[4][3] = {{0.375f, 0.625f, 0.f},
                          {0.1875f, 0.75f, 0.0625f},
                          {0.0625f, 0.75f, 0.1875f},
                          {0.f, 0.625f, 0.375f}};
  for (int a = 0; a < 4; ++a) for (int t = 0; t < 3; ++t) bp.P[a][t] = Pt[a][t];

  size_t o = 0;
  float* C1 = ws + o; o += 3ull * 1024 * 1024;
  float* p2 = ws + o; o += 3ull * 512 * 512;
  float* p3 = ws + o; o += 3ull * 256 * 256;
  float* p4 = ws + o; o += 3ull * 128 * 128;
  float* p5 = ws + o; o += 3ull * 64 * 64;

  downAll_k <<<dim3(32, 32, 3), dim3(16, 16), 0, stream>>>(img, C1, p2, p3, p4, p5);
  fblend_k  <<<dim3(8, 256),    dim3(64, 4),  0, stream>>>(img, C1, p2, p3, p4, p5,
                                                           fixs, nf, out, bp);
}

// Round 8
// 128.518 us; speedup vs baseline: 1.0309x; 1.0202x over previous
//
#include <hip/hip_runtime.h>
#include <math.h>

#define HW2048 (2048ull*2048ull)
typedef float f4 __attribute__((ext_vector_type(4)));
typedef float f2 __attribute__((ext_vector_type(2)));

struct BP {
  float P[4][3];   // composed 2-stage bilinear phase weights
  float D2[5];     // d^2 thresholds: L = sum(d2 >= D2[j])
  float cc[5];     // Ts exponent coefs (cc[l] = 4*cc[l-1])
};

__device__ __forceinline__ int ladder5(float dd, const BP& bp) {
  return (dd >= bp.D2[0]) + (dd >= bp.D2[1]) + (dd >= bp.D2[2]) +
         (dd >= bp.D2[3]) + (dd >= bp.D2[4]);
}

// ---------------- K1: img -> C1 + full pyramid p2..p5 (block-local) ---------
// C1 stores are gated: C1 is only sampled by fblend where pixel level <= 3
// (within ~sqrt(D2[3]) of a fixation); blocks beyond sqrt(D2[3])+16 px skip
// the 12MB C1 write (~73% of blocks for 4 fixations).
__global__ __launch_bounds__(256) void downAll_k(const float* __restrict__ img,
                                                 float* __restrict__ C1,
                                                 float* __restrict__ p2,
                                                 float* __restrict__ p3,
                                                 float* __restrict__ p4,
                                                 float* __restrict__ p5,
                                                 const float* __restrict__ fixs,
                                                 int nf, float c1thr) {
  __shared__ float t2[16][17];
  __shared__ float t3[8][9];
  __shared__ float t4a[4][5];
  int tx = threadIdx.x, ty = threadIdx.y;  // (16,16); grid (32,32,3)
  int X = blockIdx.x * 16 + tx;            // 0..511
  int Y = blockIdx.y * 16 + ty;            // 0..511
  int c = blockIdx.z;

  // block rect-distance to nearest fixation (img coords; block = 64x64 px)
  int XB = blockIdx.x * 64, YB = blockIdx.y * 64;
  float bD = 3.4e38f;
  for (int f = 0; f < nf; ++f) {
    float fx = fixs[2 * f], fy = fixs[2 * f + 1];
    float dx = fmaxf(fmaxf((float)XB - fx, fx - (float)(XB + 63)), 0.f);
    float dy = fmaxf(fmaxf((float)YB - fy, fy - (float)(YB + 63)), 0.f);
    bD = fminf(bD, dx * dx + dy * dy);
  }
  bool wC1 = (bD <= c1thr);

  const float* ip = img + (size_t)c * HW2048 + (size_t)(4 * Y) * 2048 + 4 * X;
  f4 r0 = __builtin_nontemporal_load((const f4*)(ip));
  f4 r1 = __builtin_nontemporal_load((const f4*)(ip + 2048));
  f4 r2 = __builtin_nontemporal_load((const f4*)(ip + 4096));
  f4 r3 = __builtin_nontemporal_load((const f4*)(ip + 6144));
  float a00 = 0.25f * (r0.x + r0.y + r1.x + r1.y);
  float a01 = 0.25f * (r0.z + r0.w + r1.z + r1.w);
  float a10 = 0.25f * (r2.x + r2.y + r3.x + r3.y);
  float a11 = 0.25f * (r2.z + r2.w + r3.z + r3.w);
  if (wC1) {
    float* cp = C1 + (size_t)c * 1048576 + (size_t)(2 * Y) * 1024 + 2 * X;
    f2 u; u.x = a00; u.y = a01; *(f2*)cp = u;
    f2 v; v.x = a10; v.y = a11; *(f2*)(cp + 1024) = v;
  }
  float m = 0.25f * (a00 + a01 + a10 + a11);
  p2[((size_t)c * 512 + Y) * 512 + X] = m;
  t2[ty][tx] = m;
  __syncthreads();
  int tid = ty * 16 + tx;
  if (tid < 64) {
    int y = tid >> 3, x = tid & 7;
    float w = 0.25f * (t2[2*y][2*x] + t2[2*y][2*x+1] + t2[2*y+1][2*x] + t2[2*y+1][2*x+1]);
    p3[((size_t)c * 256 + blockIdx.y * 8 + y) * 256 + blockIdx.x * 8 + x] = w;
    t3[y][x] = w;
  }
  __syncthreads();
  if (tid < 16) {
    int y = tid >> 2, x = tid & 3;
    float w = 0.25f * (t3[2*y][2*x] + t3[2*y][2*x+1] + t3[2*y+1][2*x] + t3[2*y+1][2*x+1]);
    p4[((size_t)c * 128 + blockIdx.y * 4 + y) * 128 + blockIdx.x * 4 + x] = w;
    t4a[y][x] = w;
  }
  __syncthreads();
  if (tid < 4) {
    int y = tid >> 1, x = tid & 1;
    float w = 0.25f * (t4a[2*y][2*x] + t4a[2*y][2*x+1] + t4a[2*y+1][2*x] + t4a[2*y+1][2*x+1]);
    p5[((size_t)c * 64 + blockIdx.y * 2 + y) * 64 + blockIdx.x * 2 + x] = w;
  }
}

// ---------------- bilinear x2 upsample coords (torch align_corners=False) ---
__device__ __forceinline__ void up_coords(int o, int n, int& i0, int& i1, float& w0) {
  int m = o >> 1;
  if (o & 1) { i0 = m; i1 = min(m + 1, n - 1); w0 = 0.75f; }
  else       { i0 = max(m - 1, 0); i1 = m;     w0 = 0.25f; }
}

// ---------------- samplers --------------------------------------------------
// 512-res buffer sampled at 2048-res with composed 2-stage weights (global)
__device__ __forceinline__ void s2c(const float* __restrict__ b, int x0, int y0,
                                    const BP& bp, float o[2][4]) {
  int t = x0 >> 2, ky = y0 >> 2, yph = y0 & 3;
  int c[3], r[3];
#pragma unroll
  for (int j = 0; j < 3; ++j) {
    c[j] = min(max(t - 1 + j, 0), 511);
    r[j] = min(max(ky - 1 + j, 0), 511);
  }
  float v[3][3];
#pragma unroll
  for (int j = 0; j < 3; ++j) {
    const float* row = b + r[j] * 512;
    v[j][0] = row[c[0]]; v[j][1] = row[c[1]]; v[j][2] = row[c[2]];
  }
  const float* wr0 = bp.P[yph];
  const float* wr1 = bp.P[yph + 1];
  float rv0[3], rv1[3];
#pragma unroll
  for (int i = 0; i < 3; ++i) {
    rv0[i] = wr0[0] * v[0][i] + wr0[1] * v[1][i] + wr0[2] * v[2][i];
    rv1[i] = wr1[0] * v[0][i] + wr1[1] * v[1][i] + wr1[2] * v[2][i];
  }
#pragma unroll
  for (int p = 0; p < 4; ++p) {
    o[0][p] = bp.P[p][0] * rv0[0] + bp.P[p][1] * rv0[1] + bp.P[p][2] * rv0[2];
    o[1][p] = bp.P[p][0] * rv1[0] + bp.P[p][1] * rv1[1] + bp.P[p][2] * rv1[2];
  }
}

// same sampling but from the block's pre-clamped LDS U-tile [4][68]
__device__ __forceinline__ void s2c_lds(const float (*t)[68], int tx, int kyr, int yph,
                                        const BP& bp, float o[2][4]) {
  float v[3][3];
#pragma unroll
  for (int j = 0; j < 3; ++j) {
    const float* row = t[kyr + j];
    v[j][0] = row[tx]; v[j][1] = row[tx + 1]; v[j][2] = row[tx + 2];
  }
  const float* wr0 = bp.P[yph];
  const float* wr1 = bp.P[yph + 1];
  float rv0[3], rv1[3];
#pragma unroll
  for (int i = 0; i < 3; ++i) {
    rv0[i] = wr0[0] * v[0][i] + wr0[1] * v[1][i] + wr0[2] * v[2][i];
    rv1[i] = wr1[0] * v[0][i] + wr1[1] * v[1][i] + wr1[2] * v[2][i];
  }
#pragma unroll
  for (int p = 0; p < 4; ++p) {
    o[0][p] = bp.P[p][0] * rv0[0] + bp.P[p][1] * rv0[1] + bp.P[p][2] * rv0[2];
    o[1][p] = bp.P[p][0] * rv1[0] + bp.P[p][1] * rv1[1] + bp.P[p][2] * rv1[2];
  }
}

// C1 (1024^2) sampled at 2048-res (single bilinear stage, global)
__device__ __forceinline__ void s1c(const float* __restrict__ b, int x0, int y0,
                                    float o[2][4]) {
  int q0 = x0 >> 1, qy = y0 >> 1;
  int c[4], r[3];
#pragma unroll
  for (int i = 0; i < 4; ++i) c[i] = min(max(q0 - 1 + i, 0), 1023);
#pragma unroll
  for (int j = 0; j < 3; ++j) r[j] = min(max(qy - 1 + j, 0), 1023);
  float v[3][4];
#pragma unroll
  for (int j = 0; j < 3; ++j) {
    const float* row = b + r[j] * 1024;
    v[j][0] = row[c[0]]; v[j][1] = row[c[1]]; v[j][2] = row[c[2]]; v[j][3] = row[c[3]];
  }
  float rv0[4], rv1[4];
#pragma unroll
  for (int i = 0; i < 4; ++i) {
    rv0[i] = 0.25f * v[0][i] + 0.75f * v[1][i];
    rv1[i] = 0.75f * v[1][i] + 0.25f * v[2][i];
  }
  o[0][0] = 0.25f * rv0[0] + 0.75f * rv0[1];
  o[0][1] = 0.75f * rv0[1] + 0.25f * rv0[2];
  o[0][2] = 0.25f * rv0[1] + 0.75f * rv0[2];
  o[0][3] = 0.75f * rv0[2] + 0.25f * rv0[3];
  o[1][0] = 0.25f * rv1[0] + 0.75f * rv1[1];
  o[1][1] = 0.75f * rv1[1] + 0.25f * rv1[2];
  o[1][2] = 0.25f * rv1[1] + 0.75f * rv1[2];
  o[1][3] = 0.75f * rv1[2] + 0.25f * rv1[3];
}

__device__ __forceinline__ void sampleL(
    int l, int ch, int x0, int y0, int tx, int kyr,
    const float* __restrict__ img, const float* __restrict__ C1,
    const float* __restrict__ p2,
    const float (*tU)[3][4][68], const BP& bp, float o[2][4]) {
  if (l == 0) {
    const float* imgc = img + (size_t)ch * HW2048;
    f4 v0 = *(const f4*)(imgc + (size_t)y0 * 2048 + x0);
    f4 v1 = *(const f4*)(imgc + (size_t)(y0 + 1) * 2048 + x0);
    o[0][0] = v0.x; o[0][1] = v0.y; o[0][2] = v0.z; o[0][3] = v0.w;
    o[1][0] = v1.x; o[1][1] = v1.y; o[1][2] = v1.z; o[1][3] = v1.w;
  } else if (l == 1) {
    s1c(C1 + (size_t)ch * 1048576, x0, y0, o);
  } else if (l == 2) {
    s2c(p2 + (size_t)ch * 262144, x0, y0, bp, o);
  } else {
    s2c_lds(tU[ch][l - 3], tx, kyr, y0 & 3, bp, o);
  }
}

// ---------------- K2: fused upchain + classify + 3-channel blend ------------
// Staging vs R7: ALL global gathers (p5->tA, p4->tM0, p3->tU0) issue in pass
// A before the first barrier; passes B (tA->tM1, tM0->tU1) and C (tM1->tU2)
// are pure-LDS. One HBM/L2 latency on the critical path instead of two.
// Per-texel math identical to R7 (values bit-identical).
__global__ __launch_bounds__(256) void fblend_k(
    const float* __restrict__ img, const float* __restrict__ C1,
    const float* __restrict__ p2, const float* __restrict__ p3,
    const float* __restrict__ p4, const float* __restrict__ p5,
    const float* __restrict__ fixs, int nf,
    float* __restrict__ out, BP bp) {
  __shared__ float tU[3][3][4][68];   // [ch][lv-3][row][col]  512-res windows
  __shared__ float tM[3][2][5][38];   // [ch][0]=mid for lv4, [1]=mid for lv5 (256-res)
  __shared__ float tA[3][5][22];      // 128-res window for lv5

  int tx = threadIdx.x, ty = threadIdx.y;       // (64,4)
  int bx = blockIdx.x, by = blockIdx.y;         // grid (8,256)
  int xs = bx * 64 + tx;                        // 0..511
  int yp = by * 4 + ty;                         // 0..1023
  int x0 = xs * 4, y0 = yp * 2;
  size_t ob0 = (size_t)y0 * 2048 + x0;

  // ---- block-level level-range bounds from fixation geometry ----
  int X0 = bx * 256, Y0 = by * 8;
  float bDmin = 3.4e38f, bDmax = 3.4e38f;
  for (int f = 0; f < nf; ++f) {
    float fx = fixs[2 * f], fy = fixs[2 * f + 1];
    float dxm = fmaxf(fmaxf((float)X0 - fx, fx - (float)(X0 + 255)), 0.f);
    float dym = fmaxf(fmaxf((float)Y0 - fy, fy - (float)(Y0 + 7)), 0.f);
    bDmin = fminf(bDmin, dxm * dxm + dym * dym);
    float dxM = fmaxf(fx - (float)X0, (float)(X0 + 255) - fx);
    float dyM = fmaxf(fy - (float)Y0, (float)(Y0 + 7) - fy);
    bDmax = fminf(bDmax, dxM * dxM + dyM * dyM);
  }
  int bLmax = ladder5(bDmax + 2.0f, bp);                 // conservative upper
  int bLmin = ladder5(fmaxf(bDmin - 2.0f, 0.f), bp);     // conservative lower

  if (bLmax == 0) {   // whole block pure img (uniform branch, no syncs inside)
#pragma unroll
    for (int ch = 0; ch < 3; ++ch) {
      const float* imgc = img + (size_t)ch * HW2048;
      f4 v0 = *(const f4*)(imgc + ob0);
      f4 v1 = *(const f4*)(imgc + ob0 + 2048);
      __builtin_nontemporal_store(v0, (f4*)(out + (size_t)ch * HW2048 + ob0));
      __builtin_nontemporal_store(v1, (f4*)(out + (size_t)ch * HW2048 + ob0 + 2048));
    }
    return;
  }

  // ---- stage the needed 512-res level windows into LDS ----
  int sLo = max(bLmin - 1, 3), sHi = min(bLmax, 5);
  int g0 = 2 * by - 1, c0 = 64 * bx - 1;                 // 512-res window base
  if (sLo <= sHi) {                                      // block-uniform
    int m0 = (g0 >> 1) - 1, n0 = (c0 >> 1) - 1;          // 256-res base
    int q0 = (m0 >> 1) - 1, s0 = (n0 >> 1) - 1;          // 128-res base
    bool lv5 = (sHi == 5), lv4 = (sLo <= 4 && sHi >= 4), lv3 = (sLo == 3);

    // ---- pass A: all pure-global gathers ----
    if (lv5 && tx < 20) {                 // tA [5][20] from p5
#pragma unroll
      for (int rr = 0; rr < 2; ++rr) {
        int r = (rr == 0) ? ty : 4;
        if (rr == 0 || ty == 0) {
          int gy = min(max(q0 + r, 0), 127);
          int gx = min(max(s0 + tx, 0), 127);
          int r0, r1, e0, e1; float wy0, wx0;
          up_coords(gy, 64, r0, r1, wy0);
          up_coords(gx, 64, e0, e1, wx0);
          float wy1 = 1.f - wy0, wx1 = 1.f - wx0;
          int i00 = r0*64+e0, i01 = r0*64+e1, i10 = r1*64+e0, i11 = r1*64+e1;
#pragma unroll
          for (int ch = 0; ch < 3; ++ch) {
            const float* s = p5 + ch * 4096;
            tA[ch][r][tx] = wy0 * (wx0 * s[i00] + wx1 * s[i01])
                          + wy1 * (wx0 * s[i10] + wx1 * s[i11]);
          }
        }
      }
    }
    if (lv4 && tx < 36) {                 // tM0 [5][36] from p4
#pragma unroll
      for (int rr = 0; rr < 2; ++rr) {
        int r = (rr == 0) ? ty : 4;
        if (rr == 0 || ty == 0) {
          int gy = min(max(m0 + r, 0), 255);
          int gx = min(max(n0 + tx, 0), 255);
          int r0, r1, e0, e1; float wy0, wx0;
          up_coords(gy, 128, r0, r1, wy0);
          up_coords(gx, 128, e0, e1, wx0);
          float wy1 = 1.f - wy0, wx1 = 1.f - wx0;
          int i00 = r0*128+e0, i01 = r0*128+e1, i10 = r1*128+e0, i11 = r1*128+e1;
#pragma unroll
          for (int ch = 0; ch < 3; ++ch) {
            const float* s = p4 + ch * 16384;
            tM[ch][0][r][tx] = wy0 * (wx0 * s[i00] + wx1 * s[i01])
                             + wy1 * (wx0 * s[i10] + wx1 * s[i11]);
          }
        }
      }
    }
    if (lv3) {                            // tU0 [4][66] from p3
#pragma unroll
      for (int cc2 = 0; cc2 < 2; ++cc2) {
        int cI = (cc2 == 0) ? tx : 64 + tx;
        if (cc2 == 0 || tx < 2) {
          int gy = min(max(g0 + ty, 0), 511);
          int gx = min(max(c0 + cI, 0), 511);
          int r0, r1, e0, e1; float wy0, wx0;
          up_coords(gy, 256, r0, r1, wy0);
          up_coords(gx, 256, e0, e1, wx0);
          float wy1 = 1.f - wy0, wx1 = 1.f - wx0;
          int i00 = r0*256+e0, i01 = r0*256+e1, i10 = r1*256+e0, i11 = r1*256+e1;
#pragma unroll
          for (int ch = 0; ch < 3; ++ch) {
            const float* s = p3 + ch * 65536;
            tU[ch][0][ty][cI] = wy0 * (wx0 * s[i00] + wx1 * s[i01])
                              + wy1 * (wx0 * s[i10] + wx1 * s[i11]);
          }
        }
      }
    }
    __syncthreads();

    // ---- pass B: LDS-only — tM1 from tA, tU1 from tM0 ----
    if (lv5 && tx < 36) {                 // tM1 [5][36] from tA
#pragma unroll
      for (int rr = 0; rr < 2; ++rr) {
        int r = (rr == 0) ? ty : 4;
        if (rr == 0 || ty == 0) {
          int gy = min(max(m0 + r, 0), 255);
          int gx = min(max(n0 + tx, 0), 255);
          int r0, r1, e0, e1; float wy0, wx0;
          up_coords(gy, 128, r0, r1, wy0);
          up_coords(gx, 128, e0, e1, wx0);
          float wy1 = 1.f - wy0, wx1 = 1.f - wx0;
          int a0 = r0 - q0, a1 = r1 - q0, b0 = e0 - s0, b1 = e1 - s0;
#pragma unroll
          for (int ch = 0; ch < 3; ++ch)
            tM[ch][1][r][tx] = wy0 * (wx0 * tA[ch][a0][b0] + wx1 * tA[ch][a0][b1])
                             + wy1 * (wx0 * tA[ch][a1][b0] + wx1 * tA[ch][a1][b1]);
        }
      }
    }
    if (lv4) {                            // tU1 [4][66] from tM0
#pragma unroll
      for (int cc2 = 0; cc2 < 2; ++cc2) {
        int cI = (cc2 == 0) ? tx : 64 + tx;
        if (cc2 == 0 || tx < 2) {
          int gy = min(max(g0 + ty, 0), 511);
          int gx = min(max(c0 + cI, 0), 511);
          int r0, r1, e0, e1; float wy0, wx0;
          up_coords(gy, 256, r0, r1, wy0);
          up_coords(gx, 256, e0, e1, wx0);
          float wy1 = 1.f - wy0, wx1 = 1.f - wx0;
          int a0 = r0 - m0, a1 = r1 - m0, b0 = e0 - n0, b1 = e1 - n0;
#pragma unroll
          for (int ch = 0; ch < 3; ++ch)
            tU[ch][1][ty][cI] = wy0 * (wx0 * tM[ch][0][a0][b0] + wx1 * tM[ch][0][a0][b1])
                              + wy1 * (wx0 * tM[ch][0][a1][b0] + wx1 * tM[ch][0][a1][b1]);
        }
      }
    }
    __syncthreads();

    // ---- pass C: tU2 from tM1 ----
    if (lv5) {
#pragma unroll
      for (int cc2 = 0; cc2 < 2; ++cc2) {
        int cI = (cc2 == 0) ? tx : 64 + tx;
        if (cc2 == 0 || tx < 2) {
          int gy = min(max(g0 + ty, 0), 511);
          int gx = min(max(c0 + cI, 0), 511);
          int r0, r1, e0, e1; float wy0, wx0;
          up_coords(gy, 256, r0, r1, wy0);
          up_coords(gx, 256, e0, e1, wx0);
          float wy1 = 1.f - wy0, wx1 = 1.f - wx0;
          int a0 = r0 - m0, a1 = r1 - m0, b0 = e0 - n0, b1 = e1 - n0;
#pragma unroll
          for (int ch = 0; ch < 3; ++ch)
            tU[ch][2][ty][cI] = wy0 * (wx0 * tM[ch][1][a0][b0] + wx1 * tM[ch][1][a0][b1])
                              + wy1 * (wx0 * tM[ch][1][a1][b0] + wx1 * tM[ch][1][a1][b1]);
        }
      }
    }
    __syncthreads();
  }
  // (no __syncthreads below this point; per-thread early-outs are safe)

  // ---- per-span min squared distance over fixations ----
  float d2[2][4];
#pragma unroll
  for (int j = 0; j < 2; ++j)
#pragma unroll
    for (int i = 0; i < 4; ++i) d2[j][i] = 3.4e38f;
  for (int f = 0; f < nf; ++f) {
    float dx0 = (float)x0 - fixs[2 * f], dy0 = (float)y0 - fixs[2 * f + 1];
#pragma unroll
    for (int j = 0; j < 2; ++j) {
      float dy = dy0 + (float)j, dy2 = dy * dy;
#pragma unroll
      for (int i = 0; i < 4; ++i) {
        float dx = dx0 + (float)i;
        d2[j][i] = fminf(d2[j][i], dx * dx + dy2);
      }
    }
  }

  bool uniformB = (bLmin == bLmax);
  int lmax;
  bool mixed;
  if (uniformB) {
    lmax = bLmax; mixed = false;
  } else {
    float dmn = d2[0][0], dmx = d2[0][0];
#pragma unroll
    for (int j = 0; j < 2; ++j)
#pragma unroll
      for (int i = 0; i < 4; ++i) {
        dmn = fminf(dmn, d2[j][i]);
        dmx = fmaxf(dmx, d2[j][i]);
      }
    lmax = ladder5(dmx, bp);
    int lmin = ladder5(dmn, bp);
    mixed = (lmin != lmax);
  }

  if (lmax == 0) {   // span pure img
#pragma unroll
    for (int ch = 0; ch < 3; ++ch) {
      const float* imgc = img + (size_t)ch * HW2048;
      f4 v0 = *(const f4*)(imgc + ob0);
      f4 v1 = *(const f4*)(imgc + ob0 + 2048);
      __builtin_nontemporal_store(v0, (f4*)(out + (size_t)ch * HW2048 + ob0));
      __builtin_nontemporal_store(v1, (f4*)(out + (size_t)ch * HW2048 + ob0 + 2048));
    }
    return;
  }

  float thr  = (lmax == 1) ? bp.D2[0] : (lmax == 2) ? bp.D2[1] :
               (lmax == 3) ? bp.D2[2] : (lmax == 4) ? bp.D2[3] : bp.D2[4];
  float cm_A = (lmax == 1) ? bp.cc[0] : (lmax == 2) ? bp.cc[1] :
               (lmax == 3) ? bp.cc[2] : (lmax == 4) ? bp.cc[3] : bp.cc[4];
  float cm_B = (lmax <= 2) ? bp.cc[0] : (lmax == 3) ? bp.cc[1] :
               (lmax == 4) ? bp.cc[2] : bp.cc[3];
  bool top5 = (lmax >= 5);

  // ---- per-pixel B (fast-math), shared by all channels ----
  float Bv[2][4];
  bool  tp[2][4];
#pragma unroll
  for (int j = 0; j < 2; ++j)
#pragma unroll
    for (int i = 0; i < 4; ++i) {
      float dd = d2[j][i];
      bool top = uniformB ? true : (dd >= thr);
      tp[j][i] = top;
      float d = dd * __frsqrt_rn(dd);
      float R = 18.75f * __frcp_rn(d + 18.75f);
      float R2 = R * R;
      float cm = top ? cm_A : cm_B;
      float tsm = __expf(-cm * R2);                 // Ts[l-1]
      float t2 = tsm * tsm;
      float tsL = (top && top5) ? 0.f : t2 * t2;    // Ts[l] = Ts[l-1]^4
      float B = (0.5f - tsL) * __frcp_rn(tsm - tsL + 1e-5f);
      if (!top && lmax == 1) B = 0.f;
      Bv[j][i] = B;
    }

  // ---- per-channel sampling + blend ----
  int kyr = ty >> 1;   // row offset of this span inside the LDS window
#pragma unroll
  for (int ch = 0; ch < 3; ++ch) {
    float sA[2][4], sB[2][4], sC[2][4];
    sampleL(lmax,     ch, x0, y0, tx, kyr, img, C1, p2, tU, bp, sA);
    sampleL(lmax - 1, ch, x0, y0, tx, kyr, img, C1, p2, tU, bp, sB);
#pragma unroll
    for (int j = 0; j < 2; ++j)
#pragma unroll
      for (int i = 0; i < 4; ++i) sC[j][i] = sB[j][i];
    if (mixed && lmax >= 2)
      sampleL(lmax - 2, ch, x0, y0, tx, kyr, img, C1, p2, tU, bp, sC);

    float res[2][4];
#pragma unroll
    for (int j = 0; j < 2; ++j)
#pragma unroll
      for (int i = 0; i < 4; ++i) {
        float B = Bv[j][i];
        bool top = tp[j][i];
        float hi = top ? sA[j][i] : sB[j][i];
        float lo = top ? sB[j][i] : sC[j][i];
        res[j][i] = B * lo + (1.f - B) * hi;
      }

    f4 v0, v1;
    v0.x = res[0][0]; v0.y = res[0][1]; v0.z = res[0][2]; v0.w = res[0][3];
    v1.x = res[1][0]; v1.y = res[1][1]; v1.z = res[1][2]; v1.w = res[1][3];
    __builtin_nontemporal_store(v0, (f4*)(out + (size_t)ch * HW2048 + ob0));
    __builtin_nontemporal_store(v1, (f4*)(out + (size_t)ch * HW2048 + ob0 + 2048));
  }
}

extern "C" void kernel_launch(void* const* d_in, const int* in_sizes, int n_in,
                              void* d_out, int out_size, void* d_ws, size_t ws_size,
                              hipStream_t stream) {
  const float* img  = (const float*)d_in[0];
  const float* fixs = (const float*)d_in[1];
  int nf = in_sizes[1] / 2;
  float* out = (float*)d_out;
  float* ws  = (float*)d_ws;

  BP bp;
  const double sig = 0.248, Kd = 3.0, Pd = 7.5, Ad = 2.5;
  double obv = sqrt(log(2.0) / Kd) * sig;
  for (int j = 0; j < 5; ++j) {
    double om = obv * pow(2.0, 2 - j);
    double Dj = Pd * Ad * (1.0 / om - 1.0);
    bp.D2[j] = (float)(Dj * Dj);
  }
  for (int X = 0; X < 5; ++X)
    bp.cc[X] = (float)(Kd * pow(2.0, 2.0 * (X - 2)) / (sig * sig));
  const float Pt[4][3] = {{0.375f, 0.625f, 0.f},
                          {0.1875f, 0.75f, 0.0625f},
                          {0.0625f, 0.75f, 0.1875f},
                          {0.f, 0.625f, 0.375f}};
  for (int a = 0; a < 4; ++a) for (int t = 0; t < 3; ++t) bp.P[a][t] = Pt[a][t];

  // C1 write gate: needed only within sqrt(D2[3]) + 16 px of a fixation
  double rC1 = sqrt((double)bp.D2[3]) + 16.0;
  float c1thr = (float)(rC1 * rC1);

  size_t o = 0;
  float* C1 = ws + o; o += 3ull * 1024 * 1024;
  float* p2 = ws + o; o += 3ull * 512 * 512;
  float* p3 = ws + o; o += 3ull * 256 * 256;
  float* p4 = ws + o; o += 3ull * 128 * 128;
  float* p5 = ws + o; o += 3ull * 64 * 64;

  downAll_k <<<dim3(32, 32, 3), dim3(16, 16), 0, stream>>>(img, C1, p2, p3, p4, p5,
                                                           fixs, nf, c1thr);
  fblend_k  <<<dim3(8, 256),    dim3(64, 4),  0, stream>>>(img, C1, p2, p3, p4, p5,
                                                           fixs, nf, out, bp);
}

// Round 9
// 127.197 us; speedup vs baseline: 1.0416x; 1.0104x over previous
//
#include <hip/hip_runtime.h>
#include <math.h>

#define HW2048 (2048ull*2048ull)
typedef float f4 __attribute__((ext_vector_type(4)));
typedef float f2 __attribute__((ext_vector_type(2)));

struct BP {
  float P[4][3];   // composed 2-stage bilinear phase weights
  float D2[5];     // d^2 thresholds: L = sum(d2 >= D2[j])
  float cc[5];     // Ts exponent coefs (cc[l] = 4*cc[l-1])
};

__device__ __forceinline__ int ladder5(float dd, const BP& bp) {
  return (dd >= bp.D2[0]) + (dd >= bp.D2[1]) + (dd >= bp.D2[2]) +
         (dd >= bp.D2[3]) + (dd >= bp.D2[4]);
}

// ---------------- K1: img -> C1 + full pyramid p2..p5 (block-local) ---------
// Store gating: C1 only sampled where pixel level <= 1 (d <~ 148 px of a
// fixation); p2 only for levels 2-3 paths (d <~ 307 px). Tiles beyond the
// per-buffer radius skip the store (gate uses tile rect-distance <= tap
// distance; 16-px margin >> float noise + tap halos).
__global__ __launch_bounds__(256) void downAll_k(const float* __restrict__ img,
                                                 float* __restrict__ C1,
                                                 float* __restrict__ p2,
                                                 float* __restrict__ p3,
                                                 float* __restrict__ p4,
                                                 float* __restrict__ p5,
                                                 const float* __restrict__ fixs,
                                                 int nf, float c1thr, float p2thr) {
  __shared__ float t2[16][17];
  __shared__ float t3[8][9];
  __shared__ float t4a[4][5];
  int tx = threadIdx.x, ty = threadIdx.y;  // (16,16); grid (32,32,3)
  int X = blockIdx.x * 16 + tx;            // 0..511
  int Y = blockIdx.y * 16 + ty;            // 0..511
  int c = blockIdx.z;

  // block rect-distance to nearest fixation (img coords; block = 64x64 px)
  int XB = blockIdx.x * 64, YB = blockIdx.y * 64;
  float bD = 3.4e38f;
  for (int f = 0; f < nf; ++f) {
    float fx = fixs[2 * f], fy = fixs[2 * f + 1];
    float dx = fmaxf(fmaxf((float)XB - fx, fx - (float)(XB + 63)), 0.f);
    float dy = fmaxf(fmaxf((float)YB - fy, fy - (float)(YB + 63)), 0.f);
    bD = fminf(bD, dx * dx + dy * dy);
  }
  bool wC1 = (bD <= c1thr);
  bool wP2 = (bD <= p2thr);

  const float* ip = img + (size_t)c * HW2048 + (size_t)(4 * Y) * 2048 + 4 * X;
  f4 r0 = __builtin_nontemporal_load((const f4*)(ip));
  f4 r1 = __builtin_nontemporal_load((const f4*)(ip + 2048));
  f4 r2 = __builtin_nontemporal_load((const f4*)(ip + 4096));
  f4 r3 = __builtin_nontemporal_load((const f4*)(ip + 6144));
  float a00 = 0.25f * (r0.x + r0.y + r1.x + r1.y);
  float a01 = 0.25f * (r0.z + r0.w + r1.z + r1.w);
  float a10 = 0.25f * (r2.x + r2.y + r3.x + r3.y);
  float a11 = 0.25f * (r2.z + r2.w + r3.z + r3.w);
  if (wC1) {
    float* cp = C1 + (size_t)c * 1048576 + (size_t)(2 * Y) * 1024 + 2 * X;
    f2 u; u.x = a00; u.y = a01; *(f2*)cp = u;
    f2 v; v.x = a10; v.y = a11; *(f2*)(cp + 1024) = v;
  }
  float m = 0.25f * (a00 + a01 + a10 + a11);
  if (wP2) p2[((size_t)c * 512 + Y) * 512 + X] = m;
  t2[ty][tx] = m;
  __syncthreads();
  int tid = ty * 16 + tx;
  if (tid < 64) {
    int y = tid >> 3, x = tid & 7;
    float w = 0.25f * (t2[2*y][2*x] + t2[2*y][2*x+1] + t2[2*y+1][2*x] + t2[2*y+1][2*x+1]);
    p3[((size_t)c * 256 + blockIdx.y * 8 + y) * 256 + blockIdx.x * 8 + x] = w;
    t3[y][x] = w;
  }
  __syncthreads();
  if (tid < 16) {
    int y = tid >> 2, x = tid & 3;
    float w = 0.25f * (t3[2*y][2*x] + t3[2*y][2*x+1] + t3[2*y+1][2*x] + t3[2*y+1][2*x+1]);
    p4[((size_t)c * 128 + blockIdx.y * 4 + y) * 128 + blockIdx.x * 4 + x] = w;
    t4a[y][x] = w;
  }
  __syncthreads();
  if (tid < 4) {
    int y = tid >> 1, x = tid & 1;
    float w = 0.25f * (t4a[2*y][2*x] + t4a[2*y][2*x+1] + t4a[2*y+1][2*x] + t4a[2*y+1][2*x+1]);
    p5[((size_t)c * 64 + blockIdx.y * 2 + y) * 64 + blockIdx.x * 2 + x] = w;
  }
}

// ---------------- bilinear x2 upsample coords (torch align_corners=False) ---
__device__ __forceinline__ void up_coords(int o, int n, int& i0, int& i1, float& w0) {
  int m = o >> 1;
  if (o & 1) { i0 = m; i1 = min(m + 1, n - 1); w0 = 0.75f; }
  else       { i0 = max(m - 1, 0); i1 = m;     w0 = 0.25f; }
}

// ---------------- samplers --------------------------------------------------
// 512-res buffer sampled at 2048-res with composed 2-stage weights (global)
__device__ __forceinline__ void s2c(const float* __restrict__ b, int x0, int y0,
                                    const BP& bp, float o[2][4]) {
  int t = x0 >> 2, ky = y0 >> 2, yph = y0 & 3;
  int c[3], r[3];
#pragma unroll
  for (int j = 0; j < 3; ++j) {
    c[j] = min(max(t - 1 + j, 0), 511);
    r[j] = min(max(ky - 1 + j, 0), 511);
  }
  float v[3][3];
#pragma unroll
  for (int j = 0; j < 3; ++j) {
    const float* row = b + r[j] * 512;
    v[j][0] = row[c[0]]; v[j][1] = row[c[1]]; v[j][2] = row[c[2]];
  }
  const float* wr0 = bp.P[yph];
  const float* wr1 = bp.P[yph + 1];
  float rv0[3], rv1[3];
#pragma unroll
  for (int i = 0; i < 3; ++i) {
    rv0[i] = wr0[0] * v[0][i] + wr0[1] * v[1][i] + wr0[2] * v[2][i];
    rv1[i] = wr1[0] * v[0][i] + wr1[1] * v[1][i] + wr1[2] * v[2][i];
  }
#pragma unroll
  for (int p = 0; p < 4; ++p) {
    o[0][p] = bp.P[p][0] * rv0[0] + bp.P[p][1] * rv0[1] + bp.P[p][2] * rv0[2];
    o[1][p] = bp.P[p][0] * rv1[0] + bp.P[p][1] * rv1[1] + bp.P[p][2] * rv1[2];
  }
}

// same sampling but from the block's pre-clamped LDS U-tile [4][68]
__device__ __forceinline__ void s2c_lds(const float (*t)[68], int tx, int kyr, int yph,
                                        const BP& bp, float o[2][4]) {
  float v[3][3];
#pragma unroll
  for (int j = 0; j < 3; ++j) {
    const float* row = t[kyr + j];
    v[j][0] = row[tx]; v[j][1] = row[tx + 1]; v[j][2] = row[tx + 2];
  }
  const float* wr0 = bp.P[yph];
  const float* wr1 = bp.P[yph + 1];
  float rv0[3], rv1[3];
#pragma unroll
  for (int i = 0; i < 3; ++i) {
    rv0[i] = wr0[0] * v[0][i] + wr0[1] * v[1][i] + wr0[2] * v[2][i];
    rv1[i] = wr1[0] * v[0][i] + wr1[1] * v[1][i] + wr1[2] * v[2][i];
  }
#pragma unroll
  for (int p = 0; p < 4; ++p) {
    o[0][p] = bp.P[p][0] * rv0[0] + bp.P[p][1] * rv0[1] + bp.P[p][2] * rv0[2];
    o[1][p] = bp.P[p][0] * rv1[0] + bp.P[p][1] * rv1[1] + bp.P[p][2] * rv1[2];
  }
}

// C1 (1024^2) sampled at 2048-res (single bilinear stage, global)
__device__ __forceinline__ void s1c(const float* __restrict__ b, int x0, int y0,
                                    float o[2][4]) {
  int q0 = x0 >> 1, qy = y0 >> 1;
  int c[4], r[3];
#pragma unroll
  for (int i = 0; i < 4; ++i) c[i] = min(max(q0 - 1 + i, 0), 1023);
#pragma unroll
  for (int j = 0; j < 3; ++j) r[j] = min(max(qy - 1 + j, 0), 1023);
  float v[3][4];
#pragma unroll
  for (int j = 0; j < 3; ++j) {
    const float* row = b + r[j] * 1024;
    v[j][0] = row[c[0]]; v[j][1] = row[c[1]]; v[j][2] = row[c[2]]; v[j][3] = row[c[3]];
  }
  float rv0[4], rv1[4];
#pragma unroll
  for (int i = 0; i < 4; ++i) {
    rv0[i] = 0.25f * v[0][i] + 0.75f * v[1][i];
    rv1[i] = 0.75f * v[1][i] + 0.25f * v[2][i];
  }
  o[0][0] = 0.25f * rv0[0] + 0.75f * rv0[1];
  o[0][1] = 0.75f * rv0[1] + 0.25f * rv0[2];
  o[0][2] = 0.25f * rv0[1] + 0.75f * rv0[2];
  o[0][3] = 0.75f * rv0[2] + 0.25f * rv0[3];
  o[1][0] = 0.25f * rv1[0] + 0.75f * rv1[1];
  o[1][1] = 0.75f * rv1[1] + 0.25f * rv1[2];
  o[1][2] = 0.25f * rv1[1] + 0.75f * rv1[2];
  o[1][3] = 0.75f * rv1[2] + 0.25f * rv1[3];
}

__device__ __forceinline__ void sampleL(
    int l, int ch, int x0, int y0, int tx, int kyr,
    const float* __restrict__ img, const float* __restrict__ C1,
    const float* __restrict__ p2,
    const float (*tU)[3][4][68], const BP& bp, float o[2][4]) {
  if (l == 0) {
    const float* imgc = img + (size_t)ch * HW2048;
    f4 v0 = *(const f4*)(imgc + (size_t)y0 * 2048 + x0);
    f4 v1 = *(const f4*)(imgc + (size_t)(y0 + 1) * 2048 + x0);
    o[0][0] = v0.x; o[0][1] = v0.y; o[0][2] = v0.z; o[0][3] = v0.w;
    o[1][0] = v1.x; o[1][1] = v1.y; o[1][2] = v1.z; o[1][3] = v1.w;
  } else if (l == 1) {
    s1c(C1 + (size_t)ch * 1048576, x0, y0, o);
  } else if (l == 2) {
    s2c(p2 + (size_t)ch * 262144, x0, y0, bp, o);
  } else {
    s2c_lds(tU[ch][l - 3], tx, kyr, y0 & 3, bp, o);
  }
}

// ---------------- K2: fused upchain + classify + 3-channel blend ------------
// Staging vs R8: TWO phases instead of three. Pass A: all global gathers
// (p5->tA, p4->tM0, p3->tU0). Pass B: tU1 from tM0, and tU2 directly from tA
// with the tM1 taps recomputed in registers using the exact staged formulas
// (bit-identical values; trades ~100 idle-VALU FMA for a barrier + the tM1
// LDS round-trip).
__global__ __launch_bounds__(256) void fblend_k(
    const float* __restrict__ img, const float* __restrict__ C1,
    const float* __restrict__ p2, const float* __restrict__ p3,
    const float* __restrict__ p4, const float* __restrict__ p5,
    const float* __restrict__ fixs, int nf,
    float* __restrict__ out, BP bp) {
  __shared__ float tU[3][3][4][68];   // [ch][lv-3][row][col]  512-res windows
  __shared__ float tM[3][5][38];      // 256-res window from p4 (for lv4)
  __shared__ float tA[3][5][22];      // 128-res window from p5 (for lv5)

  int tx = threadIdx.x, ty = threadIdx.y;       // (64,4)
  int bx = blockIdx.x, by = blockIdx.y;         // grid (8,256)
  int xs = bx * 64 + tx;                        // 0..511
  int yp = by * 4 + ty;                         // 0..1023
  int x0 = xs * 4, y0 = yp * 2;
  size_t ob0 = (size_t)y0 * 2048 + x0;

  // ---- block-level level-range bounds from fixation geometry ----
  int X0 = bx * 256, Y0 = by * 8;
  float bDmin = 3.4e38f, bDmax = 3.4e38f;
  for (int f = 0; f < nf; ++f) {
    float fx = fixs[2 * f], fy = fixs[2 * f + 1];
    float dxm = fmaxf(fmaxf((float)X0 - fx, fx - (float)(X0 + 255)), 0.f);
    float dym = fmaxf(fmaxf((float)Y0 - fy, fy - (float)(Y0 + 7)), 0.f);
    bDmin = fminf(bDmin, dxm * dxm + dym * dym);
    float dxM = fmaxf(fx - (float)X0, (float)(X0 + 255) - fx);
    float dyM = fmaxf(fy - (float)Y0, (float)(Y0 + 7) - fy);
    bDmax = fminf(bDmax, dxM * dxM + dyM * dyM);
  }
  int bLmax = ladder5(bDmax + 2.0f, bp);                 // conservative upper
  int bLmin = ladder5(fmaxf(bDmin - 2.0f, 0.f), bp);     // conservative lower

  if (bLmax == 0) {   // whole block pure img (uniform branch, no syncs inside)
#pragma unroll
    for (int ch = 0; ch < 3; ++ch) {
      const float* imgc = img + (size_t)ch * HW2048;
      f4 v0 = *(const f4*)(imgc + ob0);
      f4 v1 = *(const f4*)(imgc + ob0 + 2048);
      __builtin_nontemporal_store(v0, (f4*)(out + (size_t)ch * HW2048 + ob0));
      __builtin_nontemporal_store(v1, (f4*)(out + (size_t)ch * HW2048 + ob0 + 2048));
    }
    return;
  }

  // ---- stage the needed 512-res level windows into LDS ----
  int sLo = max(bLmin - 1, 3), sHi = min(bLmax, 5);
  int g0 = 2 * by - 1, c0 = 64 * bx - 1;                 // 512-res window base
  if (sLo <= sHi) {                                      // block-uniform
    int m0 = (g0 >> 1) - 1, n0 = (c0 >> 1) - 1;          // 256-res base
    int q0 = (m0 >> 1) - 1, s0 = (n0 >> 1) - 1;          // 128-res base
    bool lv5 = (sHi == 5), lv4 = (sLo <= 4 && sHi >= 4), lv3 = (sLo == 3);

    // ---- pass A: all pure-global gathers ----
    if (lv5 && tx < 20) {                 // tA [5][20] from p5
#pragma unroll
      for (int rr = 0; rr < 2; ++rr) {
        int r = (rr == 0) ? ty : 4;
        if (rr == 0 || ty == 0) {
          int gy = min(max(q0 + r, 0), 127);
          int gx = min(max(s0 + tx, 0), 127);
          int r0, r1, e0, e1; float wy0, wx0;
          up_coords(gy, 64, r0, r1, wy0);
          up_coords(gx, 64, e0, e1, wx0);
          float wy1 = 1.f - wy0, wx1 = 1.f - wx0;
          int i00 = r0*64+e0, i01 = r0*64+e1, i10 = r1*64+e0, i11 = r1*64+e1;
#pragma unroll
          for (int ch = 0; ch < 3; ++ch) {
            const float* s = p5 + ch * 4096;
            tA[ch][r][tx] = wy0 * (wx0 * s[i00] + wx1 * s[i01])
                          + wy1 * (wx0 * s[i10] + wx1 * s[i11]);
          }
        }
      }
    }
    if (lv4 && tx < 36) {                 // tM [5][36] from p4
#pragma unroll
      for (int rr = 0; rr < 2; ++rr) {
        int r = (rr == 0) ? ty : 4;
        if (rr == 0 || ty == 0) {
          int gy = min(max(m0 + r, 0), 255);
          int gx = min(max(n0 + tx, 0), 255);
          int r0, r1, e0, e1; float wy0, wx0;
          up_coords(gy, 128, r0, r1, wy0);
          up_coords(gx, 128, e0, e1, wx0);
          float wy1 = 1.f - wy0, wx1 = 1.f - wx0;
          int i00 = r0*128+e0, i01 = r0*128+e1, i10 = r1*128+e0, i11 = r1*128+e1;
#pragma unroll
          for (int ch = 0; ch < 3; ++ch) {
            const float* s = p4 + ch * 16384;
            tM[ch][r][tx] = wy0 * (wx0 * s[i00] + wx1 * s[i01])
                          + wy1 * (wx0 * s[i10] + wx1 * s[i11]);
          }
        }
      }
    }
    if (lv3) {                            // tU0 [4][66] from p3
#pragma unroll
      for (int cc2 = 0; cc2 < 2; ++cc2) {
        int cI = (cc2 == 0) ? tx : 64 + tx;
        if (cc2 == 0 || tx < 2) {
          int gy = min(max(g0 + ty, 0), 511);
          int gx = min(max(c0 + cI, 0), 511);
          int r0, r1, e0, e1; float wy0, wx0;
          up_coords(gy, 256, r0, r1, wy0);
          up_coords(gx, 256, e0, e1, wx0);
          float wy1 = 1.f - wy0, wx1 = 1.f - wx0;
          int i00 = r0*256+e0, i01 = r0*256+e1, i10 = r1*256+e0, i11 = r1*256+e1;
#pragma unroll
          for (int ch = 0; ch < 3; ++ch) {
            const float* s = p3 + ch * 65536;
            tU[ch][0][ty][cI] = wy0 * (wx0 * s[i00] + wx1 * s[i01])
                              + wy1 * (wx0 * s[i10] + wx1 * s[i11]);
          }
        }
      }
    }
    __syncthreads();

    // ---- pass B: LDS-only — tU1 from tM; tU2 from tA (tM1 taps in regs) ----
    if (lv4 || lv5) {
#pragma unroll
      for (int cc2 = 0; cc2 < 2; ++cc2) {
        int cI = (cc2 == 0) ? tx : 64 + tx;
        if (cc2 == 0 || tx < 2) {
          int gy = min(max(g0 + ty, 0), 511);
          int gx = min(max(c0 + cI, 0), 511);
          int R0, R1, E0, E1; float WY0, WX0;
          up_coords(gy, 256, R0, R1, WY0);
          up_coords(gx, 256, E0, E1, WX0);
          float WY1 = 1.f - WY0, WX1 = 1.f - WX0;
          if (lv4) {
            int a0 = R0 - m0, a1 = R1 - m0, b0 = E0 - n0, b1 = E1 - n0;
#pragma unroll
            for (int ch = 0; ch < 3; ++ch)
              tU[ch][1][ty][cI] = WY0 * (WX0 * tM[ch][a0][b0] + WX1 * tM[ch][a0][b1])
                                + WY1 * (WX0 * tM[ch][a1][b0] + WX1 * tM[ch][a1][b1]);
          }
          if (lv5) {
            // tM1 taps recomputed from tA with the exact staged formula
            int ra0[2], ra1[2]; float wv0[2];
            up_coords(R0, 128, ra0[0], ra1[0], wv0[0]);
            up_coords(R1, 128, ra0[1], ra1[1], wv0[1]);
            int cb0[2], cb1[2]; float wu0[2];
            up_coords(E0, 128, cb0[0], cb1[0], wu0[0]);
            up_coords(E1, 128, cb0[1], cb1[1], wu0[1]);
            int ia0[2] = {ra0[0] - q0, ra0[1] - q0};
            int ia1[2] = {ra1[0] - q0, ra1[1] - q0};
            int jb0[2] = {cb0[0] - s0, cb0[1] - s0};
            int jb1[2] = {cb1[0] - s0, cb1[1] - s0};
#pragma unroll
            for (int ch = 0; ch < 3; ++ch) {
              float tap[2][2];
#pragma unroll
              for (int a = 0; a < 2; ++a) {
                float v0a = wv0[a], v1a = 1.f - wv0[a];
#pragma unroll
                for (int b = 0; b < 2; ++b) {
                  float u0b = wu0[b], u1b = 1.f - wu0[b];
                  tap[a][b] = v0a * (u0b * tA[ch][ia0[a]][jb0[b]] + u1b * tA[ch][ia0[a]][jb1[b]])
                            + v1a * (u0b * tA[ch][ia1[a]][jb0[b]] + u1b * tA[ch][ia1[a]][jb1[b]]);
                }
              }
              tU[ch][2][ty][cI] = WY0 * (WX0 * tap[0][0] + WX1 * tap[0][1])
                                + WY1 * (WX0 * tap[1][0] + WX1 * tap[1][1]);
            }
          }
        }
      }
    }
    __syncthreads();
  }
  // (no __syncthreads below this point; per-thread early-outs are safe)

  // ---- per-span min squared distance over fixations ----
  float d2[2][4];
#pragma unroll
  for (int j = 0; j < 2; ++j)
#pragma unroll
    for (int i = 0; i < 4; ++i) d2[j][i] = 3.4e38f;
  for (int f = 0; f < nf; ++f) {
    float dx0 = (float)x0 - fixs[2 * f], dy0 = (float)y0 - fixs[2 * f + 1];
#pragma unroll
    for (int j = 0; j < 2; ++j) {
      float dy = dy0 + (float)j, dy2 = dy * dy;
#pragma unroll
      for (int i = 0; i < 4; ++i) {
        float dx = dx0 + (float)i;
        d2[j][i] = fminf(d2[j][i], dx * dx + dy2);
      }
    }
  }

  bool uniformB = (bLmin == bLmax);
  int lmax;
  bool mixed;
  if (uniformB) {
    lmax = bLmax; mixed = false;
  } else {
    float dmn = d2[0][0], dmx = d2[0][0];
#pragma unroll
    for (int j = 0; j < 2; ++j)
#pragma unroll
      for (int i = 0; i < 4; ++i) {
        dmn = fminf(dmn, d2[j][i]);
        dmx = fmaxf(dmx, d2[j][i]);
      }
    lmax = ladder5(dmx, bp);
    int lmin = ladder5(dmn, bp);
    mixed = (lmin != lmax);
  }

  if (lmax == 0) {   // span pure img
#pragma unroll
    for (int ch = 0; ch < 3; ++ch) {
      const float* imgc = img + (size_t)ch * HW2048;
      f4 v0 = *(const f4*)(imgc + ob0);
      f4 v1 = *(const f4*)(imgc + ob0 + 2048);
      __builtin_nontemporal_store(v0, (f4*)(out + (size_t)ch * HW2048 + ob0));
      __builtin_nontemporal_store(v1, (f4*)(out + (size_t)ch * HW2048 + ob0 + 2048));
    }
    return;
  }

  float thr  = (lmax == 1) ? bp.D2[0] : (lmax == 2) ? bp.D2[1] :
               (lmax == 3) ? bp.D2[2] : (lmax == 4) ? bp.D2[3] : bp.D2[4];
  float cm_A = (lmax == 1) ? bp.cc[0] : (lmax == 2) ? bp.cc[1] :
               (lmax == 3) ? bp.cc[2] : (lmax == 4) ? bp.cc[3] : bp.cc[4];
  float cm_B = (lmax <= 2) ? bp.cc[0] : (lmax == 3) ? bp.cc[1] :
               (lmax == 4) ? bp.cc[2] : bp.cc[3];
  bool top5 = (lmax >= 5);

  // ---- per-pixel B (fast-math), shared by all channels ----
  float Bv[2][4];
  bool  tp[2][4];
#pragma unroll
  for (int j = 0; j < 2; ++j)
#pragma unroll
    for (int i = 0; i < 4; ++i) {
      float dd = d2[j][i];
      bool top = uniformB ? true : (dd >= thr);
      tp[j][i] = top;
      float d = dd * __frsqrt_rn(dd);
      float R = 18.75f * __frcp_rn(d + 18.75f);
      float R2 = R * R;
      float cm = top ? cm_A : cm_B;
      float tsm = __expf(-cm * R2);                 // Ts[l-1]
      float t2 = tsm * tsm;
      float tsL = (top && top5) ? 0.f : t2 * t2;    // Ts[l] = Ts[l-1]^4
      float B = (0.5f - tsL) * __frcp_rn(tsm - tsL + 1e-5f);
      if (!top && lmax == 1) B = 0.f;
      Bv[j][i] = B;
    }

  // ---- per-channel sampling + blend ----
  int kyr = ty >> 1;   // row offset of this span inside the LDS window
#pragma unroll
  for (int ch = 0; ch < 3; ++ch) {
    float sA[2][4], sB[2][4], sC[2][4];
    sampleL(lmax,     ch, x0, y0, tx, kyr, img, C1, p2, tU, bp, sA);
    sampleL(lmax - 1, ch, x0, y0, tx, kyr, img, C1, p2, tU, bp, sB);
#pragma unroll
    for (int j = 0; j < 2; ++j)
#pragma unroll
      for (int i = 0; i < 4; ++i) sC[j][i] = sB[j][i];
    if (mixed && lmax >= 2)
      sampleL(lmax - 2, ch, x0, y0, tx, kyr, img, C1, p2, tU, bp, sC);

    float res[2][4];
#pragma unroll
    for (int j = 0; j < 2; ++j)
#pragma unroll
      for (int i = 0; i < 4; ++i) {
        float B = Bv[j][i];
        bool top = tp[j][i];
        float hi = top ? sA[j][i] : sB[j][i];
        float lo = top ? sB[j][i] : sC[j][i];
        res[j][i] = B * lo + (1.f - B) * hi;
      }

    f4 v0, v1;
    v0.x = res[0][0]; v0.y = res[0][1]; v0.z = res[0][2]; v0.w = res[0][3];
    v1.x = res[1][0]; v1.y = res[1][1]; v1.z = res[1][2]; v1.w = res[1][3];
    __builtin_nontemporal_store(v0, (f4*)(out + (size_t)ch * HW2048 + ob0));
    __builtin_nontemporal_store(v1, (f4*)(out + (size_t)ch * HW2048 + ob0 + 2048));
  }
}

extern "C" void kernel_launch(void* const* d_in, const int* in_sizes, int n_in,
                              void* d_out, int out_size, void* d_ws, size_t ws_size,
                              hipStream_t stream) {
  const float* img  = (const float*)d_in[0];
  const float* fixs = (const float*)d_in[1];
  int nf = in_sizes[1] / 2;
  float* out = (float*)d_out;
  float* ws  = (float*)d_ws;

  BP bp;
  const double sig = 0.248, Kd = 3.0, Pd = 7.5, Ad = 2.5;
  double obv = sqrt(log(2.0) / Kd) * sig;
  for (int j = 0; j < 5; ++j) {
    double om = obv * pow(2.0, 2 - j);
    double Dj = Pd * Ad * (1.0 / om - 1.0);
    bp.D2[j] = (float)(Dj * Dj);
  }
  for (int X = 0; X < 5; ++X)
    bp.cc[X] = (float)(Kd * pow(2.0, 2.0 * (X - 2)) / (sig * sig));
  const float Pt[4][3] = {{0.375f, 0.625f, 0.f},
                          {0.1875f, 0.75f, 0.0625f},
                          {0.0625f, 0.75f, 0.1875f},
                          {0.f, 0.625f, 0.375f}};
  for (int a = 0; a < 4; ++a) for (int t = 0; t < 3; ++t) bp.P[a][t] = Pt[a][t];

  // store gates: C1 used only for pixel levels <=1 (taps within sqrt(D2[2])+16);
  // p2 only for levels 2-3 paths (taps within sqrt(D2[3])+16)
  double rC1 = sqrt((double)bp.D2[2]) + 16.0;
  double rP2 = sqrt((double)bp.D2[3]) + 16.0;
  float c1thr = (float)(rC1 * rC1);
  float p2thr = (float)(rP2 * rP2);

  size_t o = 0;
  float* C1 = ws + o; o += 3ull * 1024 * 1024;
  float* p2 = ws + o; o += 3ull * 512 * 512;
  float* p3 = ws + o; o += 3ull * 256 * 256;
  float* p4 = ws + o; o += 3ull * 128 * 128;
  float* p5 = ws + o; o += 3ull * 64 * 64;

  downAll_k <<<dim3(32, 32, 3), dim3(16, 16), 0, stream>>>(img, C1, p2, p3, p4, p5,
                                                           fixs, nf, c1thr, p2thr);
  fblend_k  <<<dim3(8, 256),    dim3(64, 4),  0, stream>>>(img, C1, p2, p3, p4, p5,
                                                           fixs, nf, out, bp);
}